// Round 2
// baseline (754.052 us; speedup 1.0000x reference)
//
#include <hip/hip_runtime.h>

#define BB 16
#define LL 512
#define DD 768
#define NHEAD 12
#define HALF 256      // L/2
#define KPRES 384
#define RCNT 128      // L - K
#define UDIM 384
#define NH2 6
#define HD 64

// ---- module-scope scratch (deterministic, no atomics) ----------------------
__device__ float              g_colsum_part[BB * NHEAD * 4 * LL]; // 1.57 MB
__device__ unsigned long long g_nodep_part[BB * HALF * 4];        // 128 KB
__device__ int g_unm[BB * RCNT];
__device__ int g_srctok[BB * RCNT];
__device__ int g_srcdst[BB * RCNT];
__device__ int g_unp[BB * RCNT];

// ---------------- K_main: sim tiles (blocks 0..255, norms inline) -----------
// ----------------         + colsum partials (blocks 256..1023)   ------------
// 256 threads. Sim blocks are VALU-bound, colsum blocks are HBM-bound; they
// co-reside (~1 sim + ~3 colsum per CU) so the 201 MB score stream hides
// under the sim matmul.
__global__ void k_main(const float* __restrict__ sc, const float* __restrict__ hs) {
    __shared__ __align__(16) float As[64][20];   // rows 80 B apart
    __shared__ __align__(16) float BsT[16][68];  // [k][col], pad 68
    __shared__ float nA[64], nB[64];
    __shared__ unsigned long long cand[64][16];
    __shared__ float red[256];
    __shared__ __align__(16) float4 smc[256];    // colsum parity combine
    int blk = blockIdx.x;
    int t = threadIdx.x;

    if (blk >= 256) {
        // ---- colsum partial (b,h,128-row chunk), diag excluded, float4 ----
        int cb = blk - 256;                // 0..767
        int ic = cb & 3;
        int bh = cb >> 2;                  // b*NHEAD + h
        const float* base = sc + (size_t)bh * LL * LL;
        int i0 = ic * 128;
        int p = t >> 7;                    // row parity within chunk
        int s = t & 127;                   // float4 slot -> cols 4s..4s+3
        float4 acc = {0.f, 0.f, 0.f, 0.f};
#pragma unroll 8
        for (int i = 0; i < 64; i++) {     // ascending i within parity: fixed order
            float4 v = ((const float4*)(base + (size_t)(i0 + 2 * i + p) * LL))[s];
            acc.x += v.x; acc.y += v.y; acc.z += v.z; acc.w += v.w;
        }
#pragma unroll
        for (int c = 0; c < 4; c++) {      // subtract owned diagonals
            int cj = 4 * s + c;
            if (cj >= i0 && cj < i0 + 128 && (cj & 1) == p) {
                float d = base[(size_t)cj * LL + cj];
                if (c == 0) acc.x -= d; else if (c == 1) acc.y -= d;
                else if (c == 2) acc.z -= d; else acc.w -= d;
            }
        }
        smc[t] = acc;
        __syncthreads();
        if (t < 128) {                     // partial = evens-sum + odds-sum
            float4 e = smc[t], o = smc[t + 128];
            float4 r;
            r.x = e.x + o.x; r.y = e.y + o.y; r.z = e.z + o.z; r.w = e.w + o.w;
            ((float4*)(g_colsum_part + (size_t)cb * LL))[t] = r;
        }
        return;
    }

    // ---- sim tile + fused row-argmax (64 even-rows x 64 odd-cols) ----------
    int b = blk >> 4, it = (blk >> 2) & 3, jt = blk & 3;
    int i0 = it * 64, j0 = jt * 64;
    const float* hb = hs + (size_t)b * LL * DD;
    // norms prologue: 2 threads per row (the 8192-block norm pass is gone)
    {
        int rl = t >> 1, hf = t & 1;
        int grow = (rl < 64) ? 2 * (i0 + rl) : 2 * (j0 + rl - 64) + 1;
        const float4* rp = (const float4*)(hb + (size_t)grow * DD) + hf * 96;
        float4 ac = {0.f, 0.f, 0.f, 0.f};
#pragma unroll 4
        for (int q = 0; q < 96; q++) {
            float4 v = rp[q];
            ac.x += v.x * v.x; ac.y += v.y * v.y; ac.z += v.z * v.z; ac.w += v.w * v.w;
        }
        red[t] = (ac.x + ac.y) + (ac.z + ac.w);
        __syncthreads();
        if (t < 128) {
            float nrm = sqrtf(red[2 * t] + red[2 * t + 1]);
            if (t < 64) nA[t] = nrm; else nB[t - 64] = nrm;
        }
        __syncthreads();
    }
    int ti = t >> 4, tj = t & 15;
    float acc[4][4];
#pragma unroll
    for (int a = 0; a < 4; a++)
#pragma unroll
        for (int c = 0; c < 4; c++) acc[a][c] = 0.f;
    int sr = t >> 2, sc4 = t & 3;
    const float* arow = hb + (size_t)(2 * (i0 + sr)) * DD;
    const float* brow = hb + (size_t)(2 * (j0 + sr) + 1) * DD;
    float inA = nA[sr], inB = nB[sr];
    float4 a4 = ((const float4*)arow)[sc4];          // prefetch step 0
    float4 b4 = ((const float4*)brow)[sc4];
    a4.x /= inA; a4.y /= inA; a4.z /= inA; a4.w /= inA;
    b4.x /= inB; b4.y /= inB; b4.z /= inB; b4.w /= inB;
    for (int s = 0; s < 48; s++) {
        __syncthreads();
        *(float4*)&As[sr][4 * sc4] = a4;
        BsT[4 * sc4 + 0][sr] = b4.x;
        BsT[4 * sc4 + 1][sr] = b4.y;
        BsT[4 * sc4 + 2][sr] = b4.z;
        BsT[4 * sc4 + 3][sr] = b4.w;
        __syncthreads();
        if (s + 1 < 48) {
            int d0 = (s + 1) * 16;
            a4 = ((const float4*)(arow + d0))[sc4];
            b4 = ((const float4*)(brow + d0))[sc4];
            a4.x /= inA; a4.y /= inA; a4.z /= inA; a4.w /= inA;
            b4.x /= inB; b4.y /= inB; b4.z /= inB; b4.w /= inB;
        }
#pragma unroll
        for (int c4 = 0; c4 < 4; c4++) {
            float4 av[4], bk4[4];
#pragma unroll
            for (int a = 0; a < 4; a++) av[a] = *(const float4*)&As[ti * 4 + a][4 * c4];
#pragma unroll
            for (int k = 0; k < 4; k++) bk4[k] = *(const float4*)&BsT[4 * c4 + k][4 * tj];
#pragma unroll
            for (int k = 0; k < 4; k++) {
#pragma unroll
                for (int a = 0; a < 4; a++) {
                    float ak = ((const float*)&av[a])[k];
#pragma unroll
                    for (int c = 0; c < 4; c++)
                        acc[a][c] += ak * ((const float*)&bk4[k])[c];
                }
            }
        }
    }
#pragma unroll
    for (int a = 0; a < 4; a++) {
        unsigned long long bp = 0ULL;
#pragma unroll
        for (int c = 0; c < 4; c++) {
            int jg = j0 + tj * 4 + c;
            unsigned u = __float_as_uint(acc[a][c]);
            u = (u & 0x80000000u) ? ~u : (u | 0x80000000u);
            unsigned long long pk = ((unsigned long long)u << 32) | (unsigned long long)(255 - jg);
            if (pk > bp) bp = pk;
        }
        cand[ti * 4 + a][tj] = bp;
    }
    __syncthreads();
    if (t < 64) {
        unsigned long long m = cand[t][0];
#pragma unroll
        for (int c2 = 1; c2 < 16; c2++) { unsigned long long v = cand[t][c2]; if (v > m) m = v; }
        g_nodep_part[((size_t)b * HALF + i0 + t) * 4 + jt] = m;
    }
}

// ---------------- K_seledge: top-K select + edge ranking (unchanged) --------
__global__ void k_seledge() {
    int b = blockIdx.x, t = threadIdx.x;
    __shared__ float v[LL];
    __shared__ int pos[LL];
    __shared__ float nm[HALF];
    __shared__ int   ni[HALF];
    float imp = 0.f;
    for (int p = 0; p < NHEAD * 4; p++)
        imp += g_colsum_part[((size_t)b * NHEAD * 4 + p) * LL + t];
    v[t] = imp;
    __syncthreads();
    int cnt = 0;
    for (int k = 0; k < LL; k++) {
        float vk = v[k];
        cnt += (vk > imp) || (vk == imp && k < t);
    }
    int notp = (cnt >= KPRES) ? 1 : 0;
    pos[t] = notp;
    __syncthreads();
    for (int s = 1; s < LL; s <<= 1) {
        int add = (t >= s) ? pos[t - s] : 0;
        __syncthreads();
        pos[t] += add;
        __syncthreads();
    }
    if (notp) g_unp[b * RCNT + pos[t] - 1] = t;
    if (t < HALF) {
        unsigned long long p = g_nodep_part[((size_t)b * HALF + t) * 4 + 0];
#pragma unroll
        for (int q = 1; q < 4; q++) {
            unsigned long long w = g_nodep_part[((size_t)b * HALF + t) * 4 + q];
            if (w > p) p = w;
        }
        unsigned u = (unsigned)(p >> 32);
        unsigned bits = (u & 0x80000000u) ? (u & 0x7FFFFFFFu) : ~u;
        nm[t] = __uint_as_float(bits);
        ni[t] = 255 - (int)(p & 0xFFFFFFFFu);
    }
    __syncthreads();
    if (t < HALF) {
        float vv = nm[t];
        int cnt2 = 0;
        for (int k = 0; k < HALF; k++) {
            float vk = nm[k];
            cnt2 += (vk > vv) || (vk == vv && k < t);
        }
        if (cnt2 < RCNT) {
            g_srctok[b * RCNT + cnt2] = t;
            g_srcdst[b * RCNT + cnt2] = ni[t];
        } else {
            g_unm[b * RCNT + (cnt2 - RCNT)] = 2 * t;
        }
    }
}

// ---------------- K_tail: attn+newtok (blocks 0..15, per batch, 6 heads) ----
// ----------------         + output rows 0..384 (blocks 16..)        --------
// Attn blocks dispatched first so they overlap the 6160 BW-bound row blocks.
__global__ void k_tail(const float* __restrict__ hs,
                       const float* __restrict__ Wq, const float* __restrict__ bq,
                       const float* __restrict__ Wk, const float* __restrict__ bk,
                       const float* __restrict__ Wv, const float* __restrict__ bv,
                       const float* __restrict__ Wo, const float* __restrict__ bo,
                       float* __restrict__ out) {
    int blk = blockIdx.x;
    int t = threadIdx.x;
    __shared__ float h0[DD];
    __shared__ __align__(16) float qs[UDIM];
    __shared__ float qbk6[NH2];
    __shared__ int   toks[RCNT];
    __shared__ float red[256];
    __shared__ float att[NH2][RCNT];     // logits, then softmax weights
    __shared__ __align__(16) float buf6[NH2][DD]; // W2 (=Wk_h@q_h), then hbar
    __shared__ float ctxS[UDIM];
    __shared__ float pm[4];
    __shared__ int ss[RCNT], sd[RCNT];

    if (blk < BB) {
        // ================= fused attention for batch b, all 6 heads =========
        int b = blk;
        const float* hb = hs + (size_t)b * LL * DD;
        for (int d = t; d < DD; d += 256) h0[d] = hb[d];
        if (t < RCNT) toks[t] = g_unp[b * RCNT + t];
        __syncthreads();
        // --- q projection (per head: 4 partials of 192, same order as before)
        for (int hh = 0; hh < NH2; hh++) {
            int u = t & 63, part = t >> 6;
            float a = 0.f;
            for (int d = part * 192; d < part * 192 + 192; d++)
                a += h0[d] * Wq[(size_t)d * UDIM + hh * HD + u];
            red[t] = a;
            __syncthreads();
            if (t < HD)
                qs[hh * HD + t] = bq[hh * HD + t] + red[t] + red[t + 64] + red[t + 128] + red[t + 192];
            __syncthreads();
        }
        // --- W2[h] = Wk_h @ q_h  (logits = H . W2_h + q_h.bk_h) ---
        for (int hh = 0; hh < NH2; hh++) {
            for (int d = t; d < DD; d += 256) {
                const float4* wrow = (const float4*)(Wk + (size_t)d * UDIM + hh * HD);
                const float4* q4 = (const float4*)(qs + hh * HD);
                float4 s4 = {0.f, 0.f, 0.f, 0.f};
#pragma unroll
                for (int u4 = 0; u4 < 16; u4++) {
                    float4 w = wrow[u4], q = q4[u4];
                    s4.x += q.x * w.x; s4.y += q.y * w.y; s4.z += q.z * w.z; s4.w += q.w * w.w;
                }
                buf6[hh][d] = (s4.x + s4.y) + (s4.z + s4.w);
            }
        }
        if (t < NH2) {
            float a = 0.f;
            for (int u = 0; u < HD; u++) a += qs[t * HD + u] * bk[t * HD + u];
            qbk6[t] = a;
        }
        __syncthreads();
        // --- logits per head: 2 threads per token, half a row each ---
        for (int hh = 0; hh < NH2; hh++) {
            int tok = t >> 1, half = t & 1;
            const float4* hr4 = (const float4*)(hb + (size_t)toks[tok] * DD) + half * 96;
            const float4* wk4 = (const float4*)(&buf6[hh][0]) + half * 96;
            float4 s4 = {0.f, 0.f, 0.f, 0.f};
            for (int d4 = 0; d4 < 96; d4++) {
                float4 w = wk4[d4], x = hr4[d4];
                s4.x += w.x * x.x; s4.y += w.y * x.y; s4.z += w.z * x.z; s4.w += w.w * x.w;
            }
            red[t] = (s4.x + s4.y) + (s4.z + s4.w);
            __syncthreads();
            if (t < RCNT)
                att[hh][t] = (qbk6[hh] + red[2 * t] + red[2 * t + 1]) * 0.125f;
            __syncthreads();
        }
        // --- softmax per head (max exact; sum via wave butterfly + pair) ---
        for (int hh = 0; hh < NH2; hh++) {
            float lg = (t < RCNT) ? att[hh][t] : -1e30f;
            float m = lg;
#pragma unroll
            for (int off = 32; off >= 1; off >>= 1) m = fmaxf(m, __shfl_xor(m, off, 64));
            if ((t & 63) == 0) pm[t >> 6] = m;
            __syncthreads();
            float mx = fmaxf(pm[0], pm[1]);
            float e = (t < RCNT) ? expf(lg - mx) : 0.f;
            float sume = e;
#pragma unroll
            for (int off = 32; off >= 1; off >>= 1) sume += __shfl_xor(sume, off, 64);
            __syncthreads();
            if ((t & 63) == 0) pm[t >> 6] = sume;
            __syncthreads();
            float inv = 1.f / (pm[0] + pm[1]);
            if (t < RCNT) att[hh][t] = e * inv;
            __syncthreads();
        }
        // --- hbar[h] = sum_tok att * H_tok (ascending tok, same order) ---
        if (t < DD / 4) {
            float4 a[NH2];
#pragma unroll
            for (int hh = 0; hh < NH2; hh++) a[hh] = make_float4(0.f, 0.f, 0.f, 0.f);
            for (int s2 = 0; s2 < RCNT; s2++) {
                float4 x = ((const float4*)(hb + (size_t)toks[s2] * DD))[t];
#pragma unroll
                for (int hh = 0; hh < NH2; hh++) {
                    float w = att[hh][s2];
                    a[hh].x += w * x.x; a[hh].y += w * x.y; a[hh].z += w * x.z; a[hh].w += w * x.w;
                }
            }
#pragma unroll
            for (int hh = 0; hh < NH2; hh++) *(float4*)&buf6[hh][4 * t] = a[hh];
        }
        __syncthreads();
        // --- ctx[h] = hbar_h @ Wv_h + bv (4 partials of 192, same order) ---
        for (int hh = 0; hh < NH2; hh++) {
            int u = t & 63, part = t >> 6;
            float a = 0.f;
            for (int d = part * 192; d < part * 192 + 192; d++)
                a += buf6[hh][d] * Wv[(size_t)d * UDIM + hh * HD + u];
            red[t] = a;
            __syncthreads();
            if (t < HD)
                ctxS[hh * HD + t] = bv[hh * HD + t] + red[t] + red[t + 64] + red[t + 128] + red[t + 192];
            __syncthreads();
        }
        // --- new_token = ctx @ Wo + bo  (output row 385, serial-u order) ---
        if (t < 192) {
#pragma unroll
            for (int kk = 0; kk < 4; kk++) {
                int dd = t + 192 * kk;
                float acc = bo[dd];
                for (int u = 0; u < UDIM; u++)
                    acc += ctxS[u] * Wo[(size_t)u * DD + dd];
                out[((size_t)b * 386 + 385) * DD + dd] = acc;
            }
        }
        return;
    }

    // ================= output rows 0..384 (copy / unm / merge) ==============
    int rblk = blk - BB;
    int row = rblk % 385, b = rblk / 385;
    float4* o4 = (float4*)(out + ((size_t)b * 386 + row) * DD);
    if (row == 0) {
        if (t < 192) {
            const float4* s4 = (const float4*)(hs + (size_t)b * LL * DD);
            o4[t] = s4[t];
        }
    } else if (row <= RCNT) {
        int tok = g_unm[b * RCNT + row - 1];
        if (t < 192) {
            const float4* s4 = (const float4*)(hs + ((size_t)b * LL + tok) * DD);
            o4[t] = s4[t];
        }
    } else {
        int j = row - 1 - RCNT;
        if (t < RCNT) { ss[t] = g_srctok[b * RCNT + t]; sd[t] = g_srcdst[b * RCNT + t]; }
        __syncthreads();
        if (t < 192) {
            float4 acc = ((const float4*)(hs + ((size_t)b * LL + 2 * j + 1) * DD))[t];
            float cnt = 1.f;
            for (int s2 = 0; s2 < RCNT; s2++) {   // ascending rank == np.add.at order
                if (sd[s2] == j) {
                    float4 v = ((const float4*)(hs + ((size_t)b * LL + 2 * ss[s2]) * DD))[t];
                    acc.x += v.x; acc.y += v.y; acc.z += v.z; acc.w += v.w;
                    cnt += 1.f;
                }
            }
            float4 r;
            r.x = acc.x / cnt; r.y = acc.y / cnt; r.z = acc.z / cnt; r.w = acc.w / cnt;
            o4[t] = r;
        }
    }
}

extern "C" void kernel_launch(void* const* d_in, const int* in_sizes, int n_in,
                              void* d_out, int out_size, void* d_ws, size_t ws_size,
                              hipStream_t stream) {
    const float* hs = (const float*)d_in[0];
    const float* sc = (const float*)d_in[1];
    const float* Wq = (const float*)d_in[2];
    const float* bq = (const float*)d_in[3];
    const float* Wk = (const float*)d_in[4];
    const float* bk = (const float*)d_in[5];
    const float* Wv = (const float*)d_in[6];
    const float* bv = (const float*)d_in[7];
    const float* Wo = (const float*)d_in[8];
    const float* bo = (const float*)d_in[9];
    float* out = (float*)d_out;
    (void)d_ws; (void)ws_size;

    k_main<<<256 + BB * NHEAD * 4, 256, 0, stream>>>(sc, hs);   // sim + colsum fused
    k_seledge<<<BB, 512, 0, stream>>>();
    k_tail<<<BB + BB * 385, 256, 0, stream>>>(hs, Wq, bq, Wk, bk, Wv, bv, Wo, bo, out);
}

// Round 3
// 576.531 us; speedup vs baseline: 1.3079x; 1.3079x over previous
//
#include <hip/hip_runtime.h>

#define BB 16
#define LL 512
#define DD 768
#define NHEAD 12
#define HALF 256      // L/2
#define KPRES 384
#define RCNT 128      // L - K
#define UDIM 384
#define NH2 6
#define HD 64

// ---- module-scope scratch (deterministic, no atomics) ----------------------
__device__ float              g_colsum_part[BB * NHEAD * 4 * LL]; // 1.57 MB
__device__ unsigned long long g_nodep_part[BB * HALF * 4];        // 128 KB
__device__ int g_unm[BB * RCNT];
__device__ int g_srctok[BB * RCNT];
__device__ int g_srcdst[BB * RCNT];
__device__ int g_unp[BB * RCNT];
__device__ float g_q[BB * UDIM];        // q per (b, h*64+u)
__device__ float g_w2[BB * NH2 * DD];   // W2[b][h][d] = Wk_h[d,:] . q_h
__device__ float g_qbk[BB * NH2];       // q_h . bk_h

// ---------------- K_main: sim tiles (0..255) + colsum (256..1023) -----------
// ----------------         + q-projection (1024..1119, one per (b,h)) -------
__global__ void k_main(const float* __restrict__ sc, const float* __restrict__ hs,
                       const float* __restrict__ Wq, const float* __restrict__ bq) {
    __shared__ __align__(16) float As[64][20];   // rows 80 B apart
    __shared__ __align__(16) float BsT[16][68];  // [k][col], pad 68
    __shared__ float nA[64], nB[64];
    __shared__ unsigned long long cand[64][16];
    __shared__ float red[256];
    __shared__ __align__(16) float4 smc[256];    // colsum parity combine
    __shared__ float h0q[DD];
    int blk = blockIdx.x;
    int t = threadIdx.x;

    if (blk >= 1024) {
        // ---- q projection for (b,h): 4 partials of 192, round-0 FP order ---
        int qb = blk - 1024;
        int b = qb / NH2, h = qb % NH2;
        const float* hb = hs + (size_t)b * LL * DD;
        for (int d = t; d < DD; d += 256) h0q[d] = hb[d];
        __syncthreads();
        int u = t & 63, part = t >> 6;
        float a = 0.f;
        for (int d = part * 192; d < part * 192 + 192; d++)
            a += h0q[d] * Wq[(size_t)d * UDIM + h * HD + u];
        red[t] = a;
        __syncthreads();
        if (t < HD)
            g_q[b * UDIM + h * HD + t] =
                bq[h * HD + t] + red[t] + red[t + 64] + red[t + 128] + red[t + 192];
        return;
    }

    if (blk >= 256) {
        // ---- colsum partial (b,h,128-row chunk), diag excluded, float4 ----
        int cb = blk - 256;                // 0..767
        int ic = cb & 3;
        int bh = cb >> 2;                  // b*NHEAD + h
        const float* base = sc + (size_t)bh * LL * LL;
        int i0 = ic * 128;
        int p = t >> 7;                    // row parity within chunk
        int s = t & 127;                   // float4 slot -> cols 4s..4s+3
        float4 acc = {0.f, 0.f, 0.f, 0.f};
#pragma unroll 8
        for (int i = 0; i < 64; i++) {     // ascending i within parity: fixed order
            float4 v = ((const float4*)(base + (size_t)(i0 + 2 * i + p) * LL))[s];
            acc.x += v.x; acc.y += v.y; acc.z += v.z; acc.w += v.w;
        }
#pragma unroll
        for (int c = 0; c < 4; c++) {      // subtract owned diagonals
            int cj = 4 * s + c;
            if (cj >= i0 && cj < i0 + 128 && (cj & 1) == p) {
                float d = base[(size_t)cj * LL + cj];
                if (c == 0) acc.x -= d; else if (c == 1) acc.y -= d;
                else if (c == 2) acc.z -= d; else acc.w -= d;
            }
        }
        smc[t] = acc;
        __syncthreads();
        if (t < 128) {                     // partial = evens-sum + odds-sum
            float4 e = smc[t], o = smc[t + 128];
            float4 r;
            r.x = e.x + o.x; r.y = e.y + o.y; r.z = e.z + o.z; r.w = e.w + o.w;
            ((float4*)(g_colsum_part + (size_t)cb * LL))[t] = r;
        }
        return;
    }

    // ---- sim tile + fused row-argmax (64 even-rows x 64 odd-cols) ----------
    int b = blk >> 4, it = (blk >> 2) & 3, jt = blk & 3;
    int i0 = it * 64, j0 = jt * 64;
    const float* hb = hs + (size_t)b * LL * DD;
    // norms prologue: 2 threads per row
    {
        int rl = t >> 1, hf = t & 1;
        int grow = (rl < 64) ? 2 * (i0 + rl) : 2 * (j0 + rl - 64) + 1;
        const float4* rp = (const float4*)(hb + (size_t)grow * DD) + hf * 96;
        float4 ac = {0.f, 0.f, 0.f, 0.f};
#pragma unroll 4
        for (int q = 0; q < 96; q++) {
            float4 v = rp[q];
            ac.x += v.x * v.x; ac.y += v.y * v.y; ac.z += v.z * v.z; ac.w += v.w * v.w;
        }
        red[t] = (ac.x + ac.y) + (ac.z + ac.w);
        __syncthreads();
        if (t < 128) {
            float nrm = sqrtf(red[2 * t] + red[2 * t + 1]);
            if (t < 64) nA[t] = nrm; else nB[t - 64] = nrm;
        }
        __syncthreads();
    }
    int ti = t >> 4, tj = t & 15;
    float acc[4][4];
#pragma unroll
    for (int a = 0; a < 4; a++)
#pragma unroll
        for (int c = 0; c < 4; c++) acc[a][c] = 0.f;
    int sr = t >> 2, sc4 = t & 3;
    const float* arow = hb + (size_t)(2 * (i0 + sr)) * DD;
    const float* brow = hb + (size_t)(2 * (j0 + sr) + 1) * DD;
    float inA = nA[sr], inB = nB[sr];
    float4 a4 = ((const float4*)arow)[sc4];          // prefetch step 0
    float4 b4 = ((const float4*)brow)[sc4];
    a4.x /= inA; a4.y /= inA; a4.z /= inA; a4.w /= inA;
    b4.x /= inB; b4.y /= inB; b4.z /= inB; b4.w /= inB;
    for (int s = 0; s < 48; s++) {
        __syncthreads();
        *(float4*)&As[sr][4 * sc4] = a4;
        BsT[4 * sc4 + 0][sr] = b4.x;
        BsT[4 * sc4 + 1][sr] = b4.y;
        BsT[4 * sc4 + 2][sr] = b4.z;
        BsT[4 * sc4 + 3][sr] = b4.w;
        __syncthreads();
        if (s + 1 < 48) {
            int d0 = (s + 1) * 16;
            a4 = ((const float4*)(arow + d0))[sc4];
            b4 = ((const float4*)(brow + d0))[sc4];
            a4.x /= inA; a4.y /= inA; a4.z /= inA; a4.w /= inA;
            b4.x /= inB; b4.y /= inB; b4.z /= inB; b4.w /= inB;
        }
#pragma unroll
        for (int c4 = 0; c4 < 4; c4++) {
            float4 av[4], bk4[4];
#pragma unroll
            for (int a = 0; a < 4; a++) av[a] = *(const float4*)&As[ti * 4 + a][4 * c4];
#pragma unroll
            for (int k = 0; k < 4; k++) bk4[k] = *(const float4*)&BsT[4 * c4 + k][4 * tj];
#pragma unroll
            for (int k = 0; k < 4; k++) {
#pragma unroll
                for (int a = 0; a < 4; a++) {
                    float ak = ((const float*)&av[a])[k];
#pragma unroll
                    for (int c = 0; c < 4; c++)
                        acc[a][c] += ak * ((const float*)&bk4[k])[c];
                }
            }
        }
    }
#pragma unroll
    for (int a = 0; a < 4; a++) {
        unsigned long long bp = 0ULL;
#pragma unroll
        for (int c = 0; c < 4; c++) {
            int jg = j0 + tj * 4 + c;
            unsigned u = __float_as_uint(acc[a][c]);
            u = (u & 0x80000000u) ? ~u : (u | 0x80000000u);
            unsigned long long pk = ((unsigned long long)u << 32) | (unsigned long long)(255 - jg);
            if (pk > bp) bp = pk;
        }
        cand[ti * 4 + a][tj] = bp;
    }
    __syncthreads();
    if (t < 64) {
        unsigned long long m = cand[t][0];
#pragma unroll
        for (int c2 = 1; c2 < 16; c2++) { unsigned long long v = cand[t][c2]; if (v > m) m = v; }
        g_nodep_part[((size_t)b * HALF + i0 + t) * 4 + jt] = m;
    }
}

// ---------------- K_seledge: sel blocks 0..15 + W2 blocks 16..111 -----------
__global__ void k_seledge(const float* __restrict__ Wk, const float* __restrict__ bk) {
    int blk = blockIdx.x, t = threadIdx.x;
    __shared__ float v[LL];
    __shared__ int pos[LL];
    __shared__ float nm[HALF];
    __shared__ int   ni[HALF];
    __shared__ __align__(16) float qsl[HD];

    if (blk >= BB) {
        // ---- W2[b][h][d] = Wk_h[d,:] . q_h  (per-d order identical) --------
        int wb = blk - BB;
        int b = wb / NH2, h = wb % NH2;
        if (t < HD) qsl[t] = g_q[b * UDIM + h * HD + t];
        __syncthreads();
        if (t < 384) {
#pragma unroll
            for (int rep = 0; rep < 2; rep++) {
                int d = t + rep * 384;
                const float4* wrow = (const float4*)(Wk + (size_t)d * UDIM + h * HD);
                const float4* q4 = (const float4*)qsl;
                float4 s4 = {0.f, 0.f, 0.f, 0.f};
#pragma unroll
                for (int u4 = 0; u4 < 16; u4++) {
                    float4 w = wrow[u4], q = q4[u4];
                    s4.x += q.x * w.x; s4.y += q.y * w.y; s4.z += q.z * w.z; s4.w += q.w * w.w;
                }
                g_w2[((size_t)b * NH2 + h) * DD + d] = (s4.x + s4.y) + (s4.z + s4.w);
            }
        }
        if (t == 0) {
            float a = 0.f;
            for (int u = 0; u < HD; u++) a += qsl[u] * bk[h * HD + u];
            g_qbk[b * NH2 + h] = a;
        }
        return;
    }

    int b = blk;
    float imp = 0.f;
    for (int p = 0; p < NHEAD * 4; p++)
        imp += g_colsum_part[((size_t)b * NHEAD * 4 + p) * LL + t];
    v[t] = imp;
    __syncthreads();
    int cnt = 0;
    for (int k = 0; k < LL; k++) {
        float vk = v[k];
        cnt += (vk > imp) || (vk == imp && k < t);
    }
    int notp = (cnt >= KPRES) ? 1 : 0;
    pos[t] = notp;
    __syncthreads();
    for (int s = 1; s < LL; s <<= 1) {
        int add = (t >= s) ? pos[t - s] : 0;
        __syncthreads();
        pos[t] += add;
        __syncthreads();
    }
    if (notp) g_unp[b * RCNT + pos[t] - 1] = t;
    if (t < HALF) {
        unsigned long long p = g_nodep_part[((size_t)b * HALF + t) * 4 + 0];
#pragma unroll
        for (int q = 1; q < 4; q++) {
            unsigned long long w = g_nodep_part[((size_t)b * HALF + t) * 4 + q];
            if (w > p) p = w;
        }
        unsigned u = (unsigned)(p >> 32);
        unsigned bits = (u & 0x80000000u) ? (u & 0x7FFFFFFFu) : ~u;
        nm[t] = __uint_as_float(bits);
        ni[t] = 255 - (int)(p & 0xFFFFFFFFu);
    }
    __syncthreads();
    if (t < HALF) {
        float vv = nm[t];
        int cnt2 = 0;
        for (int k = 0; k < HALF; k++) {
            float vk = nm[k];
            cnt2 += (vk > vv) || (vk == vv && k < t);
        }
        if (cnt2 < RCNT) {
            g_srctok[b * RCNT + cnt2] = t;
            g_srcdst[b * RCNT + cnt2] = ni[t];
        } else {
            g_unm[b * RCNT + (cnt2 - RCNT)] = 2 * t;
        }
    }
}

// ---------------- K_tail: attn finish (blocks 0..15) + output rows ----------
// Logits fused over 6 heads: each token row loaded ONCE (7 sweeps -> 2).
__global__ void k_tail(const float* __restrict__ hs,
                       const float* __restrict__ Wv, const float* __restrict__ bv,
                       const float* __restrict__ Wo, const float* __restrict__ bo,
                       float* __restrict__ out) {
    int blk = blockIdx.x;
    int t = threadIdx.x;
    __shared__ float qbk6[NH2];
    __shared__ int   toks[RCNT];
    __shared__ float red[256];
    __shared__ float red6[NH2][256];
    __shared__ float att[NH2][RCNT];
    __shared__ __align__(16) float buf6[NH2][DD]; // W2, then hbar
    __shared__ float ctxS[UDIM];
    __shared__ float pm[4];
    __shared__ int ss[RCNT], sd[RCNT];

    if (blk < BB) {
        int b = blk;
        const float* hb = hs + (size_t)b * LL * DD;
        if (t < RCNT) toks[t] = g_unp[b * RCNT + t];
        if (t >= 192 && t < 192 + NH2) qbk6[t - 192] = g_qbk[b * NH2 + (t - 192)];
        {
            float* bflat = &buf6[0][0];
            const float* src = g_w2 + (size_t)b * NH2 * DD;
            for (int i = t; i < NH2 * DD; i += 256) bflat[i] = src[i];
        }
        __syncthreads();
        // --- logits, all 6 heads per row pass (per-head chains unchanged) ---
        {
            int tok = t >> 1, half = t & 1;
            const float4* hr4 = (const float4*)(hb + (size_t)toks[tok] * DD) + half * 96;
            float4 s6[NH2];
#pragma unroll
            for (int hh = 0; hh < NH2; hh++) s6[hh] = make_float4(0.f, 0.f, 0.f, 0.f);
            for (int d4 = 0; d4 < 96; d4++) {
                float4 x = hr4[d4];
#pragma unroll
                for (int hh = 0; hh < NH2; hh++) {
                    float4 w = ((const float4*)(&buf6[hh][0]) + half * 96)[d4];
                    s6[hh].x += w.x * x.x; s6[hh].y += w.y * x.y;
                    s6[hh].z += w.z * x.z; s6[hh].w += w.w * x.w;
                }
            }
#pragma unroll
            for (int hh = 0; hh < NH2; hh++)
                red6[hh][t] = (s6[hh].x + s6[hh].y) + (s6[hh].z + s6[hh].w);
        }
        __syncthreads();
        if (t < RCNT) {
#pragma unroll
            for (int hh = 0; hh < NH2; hh++)
                att[hh][t] = (qbk6[hh] + red6[hh][2 * t] + red6[hh][2 * t + 1]) * 0.125f;
        }
        __syncthreads();
        // --- softmax per head (verbatim from passing kernel) ---
        for (int hh = 0; hh < NH2; hh++) {
            float lg = (t < RCNT) ? att[hh][t] : -1e30f;
            float m = lg;
#pragma unroll
            for (int off = 32; off >= 1; off >>= 1) m = fmaxf(m, __shfl_xor(m, off, 64));
            if ((t & 63) == 0) pm[t >> 6] = m;
            __syncthreads();
            float mx = fmaxf(pm[0], pm[1]);
            float e = (t < RCNT) ? expf(lg - mx) : 0.f;
            float sume = e;
#pragma unroll
            for (int off = 32; off >= 1; off >>= 1) sume += __shfl_xor(sume, off, 64);
            __syncthreads();
            if ((t & 63) == 0) pm[t >> 6] = sume;
            __syncthreads();
            float inv = 1.f / (pm[0] + pm[1]);
            if (t < RCNT) att[hh][t] = e * inv;
            __syncthreads();
        }
        // --- hbar[h] = sum_tok att * H_tok (verbatim) ---
        if (t < DD / 4) {
            float4 a[NH2];
#pragma unroll
            for (int hh = 0; hh < NH2; hh++) a[hh] = make_float4(0.f, 0.f, 0.f, 0.f);
            for (int s2 = 0; s2 < RCNT; s2++) {
                float4 x = ((const float4*)(hb + (size_t)toks[s2] * DD))[t];
#pragma unroll
                for (int hh = 0; hh < NH2; hh++) {
                    float w = att[hh][s2];
                    a[hh].x += w * x.x; a[hh].y += w * x.y; a[hh].z += w * x.z; a[hh].w += w * x.w;
                }
            }
#pragma unroll
            for (int hh = 0; hh < NH2; hh++) *(float4*)&buf6[hh][4 * t] = a[hh];
        }
        __syncthreads();
        // --- ctx[h] = hbar_h @ Wv_h + bv (verbatim) ---
        for (int hh = 0; hh < NH2; hh++) {
            int u = t & 63, part = t >> 6;
            float a = 0.f;
            for (int d = part * 192; d < part * 192 + 192; d++)
                a += buf6[hh][d] * Wv[(size_t)d * UDIM + hh * HD + u];
            red[t] = a;
            __syncthreads();
            if (t < HD)
                ctxS[hh * HD + t] = bv[hh * HD + t] + red[t] + red[t + 64] + red[t + 128] + red[t + 192];
            __syncthreads();
        }
        // --- new_token = ctx @ Wo + bo (verbatim) ---
        if (t < 192) {
#pragma unroll
            for (int kk = 0; kk < 4; kk++) {
                int dd = t + 192 * kk;
                float acc = bo[dd];
                for (int u = 0; u < UDIM; u++)
                    acc += ctxS[u] * Wo[(size_t)u * DD + dd];
                out[((size_t)b * 386 + 385) * DD + dd] = acc;
            }
        }
        return;
    }

    // ================= output rows 0..384 (copy / unm / merge) ==============
    int rblk = blk - BB;
    int row = rblk % 385, b = rblk / 385;
    float4* o4 = (float4*)(out + ((size_t)b * 386 + row) * DD);
    if (row == 0) {
        if (t < 192) {
            const float4* s4 = (const float4*)(hs + (size_t)b * LL * DD);
            o4[t] = s4[t];
        }
    } else if (row <= RCNT) {
        int tok = g_unm[b * RCNT + row - 1];
        if (t < 192) {
            const float4* s4 = (const float4*)(hs + ((size_t)b * LL + tok) * DD);
            o4[t] = s4[t];
        }
    } else {
        int j = row - 1 - RCNT;
        if (t < RCNT) { ss[t] = g_srctok[b * RCNT + t]; sd[t] = g_srcdst[b * RCNT + t]; }
        __syncthreads();
        if (t < 192) {
            float4 acc = ((const float4*)(hs + ((size_t)b * LL + 2 * j + 1) * DD))[t];
            float cnt = 1.f;
            for (int s2 = 0; s2 < RCNT; s2++) {   // ascending rank == np.add.at order
                if (sd[s2] == j) {
                    float4 v = ((const float4*)(hs + ((size_t)b * LL + 2 * ss[s2]) * DD))[t];
                    acc.x += v.x; acc.y += v.y; acc.z += v.z; acc.w += v.w;
                    cnt += 1.f;
                }
            }
            float4 r;
            r.x = acc.x / cnt; r.y = acc.y / cnt; r.z = acc.z / cnt; r.w = acc.w / cnt;
            o4[t] = r;
        }
    }
}

extern "C" void kernel_launch(void* const* d_in, const int* in_sizes, int n_in,
                              void* d_out, int out_size, void* d_ws, size_t ws_size,
                              hipStream_t stream) {
    const float* hs = (const float*)d_in[0];
    const float* sc = (const float*)d_in[1];
    const float* Wq = (const float*)d_in[2];
    const float* bq = (const float*)d_in[3];
    const float* Wk = (const float*)d_in[4];
    const float* bk = (const float*)d_in[5];
    const float* Wv = (const float*)d_in[6];
    const float* bv = (const float*)d_in[7];
    const float* Wo = (const float*)d_in[8];
    const float* bo = (const float*)d_in[9];
    float* out = (float*)d_out;
    (void)d_ws; (void)ws_size;

    k_main<<<256 + BB * NHEAD * 4 + BB * NH2, 256, 0, stream>>>(sc, hs, Wq, bq);
    k_seledge<<<BB + BB * NH2, 512, 0, stream>>>(Wk, bk);
    k_tail<<<BB + BB * 385, 256, 0, stream>>>(hs, Wv, bv, Wo, bo, out);
}

// Round 4
// 451.368 us; speedup vs baseline: 1.6706x; 1.2773x over previous
//
#include <hip/hip_runtime.h>

#define BB 16
#define LL 512
#define DD 768
#define NHEAD 12
#define HALF 256      // L/2
#define KPRES 384
#define RCNT 128      // L - K
#define UDIM 384
#define NH2 6
#define HD 64

// ---- module-scope scratch (deterministic, no atomics) ----------------------
__device__ float              g_colsum_part[BB * NHEAD * 4 * LL]; // 1.57 MB
__device__ unsigned long long g_nodep_part[BB * HALF * 4];        // 128 KB
__device__ int g_unm[BB * RCNT];
__device__ int g_srctok[BB * RCNT];
__device__ int g_srcdst[BB * RCNT];
__device__ int g_unp[BB * RCNT];
__device__ float g_q[BB * UDIM];        // q per (b, h*64+u)
__device__ float g_w2[BB * NH2 * DD];   // W2[b][h][d] = Wk_h[d,:] . q_h
__device__ float g_qbk[BB * NH2];       // q_h . bk_h
__device__ float g_ctx[BB * UDIM];      // ctx per (b, h*64+u)

// ---------------- K_main: sim tiles (0..255) + colsum (256..1023) -----------
// ----------------         + q-projection (1024..1119, one per (b,h)) -------
__global__ void k_main(const float* __restrict__ sc, const float* __restrict__ hs,
                       const float* __restrict__ Wq, const float* __restrict__ bq) {
    __shared__ __align__(16) float As[64][20];   // rows 80 B apart
    __shared__ __align__(16) float BsT[16][68];  // [k][col], pad 68
    __shared__ float nA[64], nB[64];
    __shared__ unsigned long long cand[64][16];
    __shared__ float red[256];
    __shared__ __align__(16) float4 smc[256];    // colsum parity combine
    __shared__ float h0q[DD];
    int blk = blockIdx.x;
    int t = threadIdx.x;

    if (blk >= 1024) {
        // ---- q projection for (b,h): 4 partials of 192, round-0 FP order ---
        int qb = blk - 1024;
        int b = qb / NH2, h = qb % NH2;
        const float* hb = hs + (size_t)b * LL * DD;
        for (int d = t; d < DD; d += 256) h0q[d] = hb[d];
        __syncthreads();
        int u = t & 63, part = t >> 6;
        float a = 0.f;
        for (int d = part * 192; d < part * 192 + 192; d++)
            a += h0q[d] * Wq[(size_t)d * UDIM + h * HD + u];
        red[t] = a;
        __syncthreads();
        if (t < HD)
            g_q[b * UDIM + h * HD + t] =
                bq[h * HD + t] + red[t] + red[t + 64] + red[t + 128] + red[t + 192];
        return;
    }

    if (blk >= 256) {
        // ---- colsum partial (b,h,128-row chunk), diag excluded, float4 ----
        int cb = blk - 256;                // 0..767
        int ic = cb & 3;
        int bh = cb >> 2;                  // b*NHEAD + h
        const float* base = sc + (size_t)bh * LL * LL;
        int i0 = ic * 128;
        int p = t >> 7;                    // row parity within chunk
        int s = t & 127;                   // float4 slot -> cols 4s..4s+3
        float4 acc = {0.f, 0.f, 0.f, 0.f};
#pragma unroll 8
        for (int i = 0; i < 64; i++) {     // ascending i within parity: fixed order
            float4 v = ((const float4*)(base + (size_t)(i0 + 2 * i + p) * LL))[s];
            acc.x += v.x; acc.y += v.y; acc.z += v.z; acc.w += v.w;
        }
#pragma unroll
        for (int c = 0; c < 4; c++) {      // subtract owned diagonals
            int cj = 4 * s + c;
            if (cj >= i0 && cj < i0 + 128 && (cj & 1) == p) {
                float d = base[(size_t)cj * LL + cj];
                if (c == 0) acc.x -= d; else if (c == 1) acc.y -= d;
                else if (c == 2) acc.z -= d; else acc.w -= d;
            }
        }
        smc[t] = acc;
        __syncthreads();
        if (t < 128) {                     // partial = evens-sum + odds-sum
            float4 e = smc[t], o = smc[t + 128];
            float4 r;
            r.x = e.x + o.x; r.y = e.y + o.y; r.z = e.z + o.z; r.w = e.w + o.w;
            ((float4*)(g_colsum_part + (size_t)cb * LL))[t] = r;
        }
        return;
    }

    // ---- sim tile + fused row-argmax (64 even-rows x 64 odd-cols) ----------
    int b = blk >> 4, it = (blk >> 2) & 3, jt = blk & 3;
    int i0 = it * 64, j0 = jt * 64;
    const float* hb = hs + (size_t)b * LL * DD;
    // norms prologue: 2 threads per row
    {
        int rl = t >> 1, hf = t & 1;
        int grow = (rl < 64) ? 2 * (i0 + rl) : 2 * (j0 + rl - 64) + 1;
        const float4* rp = (const float4*)(hb + (size_t)grow * DD) + hf * 96;
        float4 ac = {0.f, 0.f, 0.f, 0.f};
#pragma unroll 4
        for (int q = 0; q < 96; q++) {
            float4 v = rp[q];
            ac.x += v.x * v.x; ac.y += v.y * v.y; ac.z += v.z * v.z; ac.w += v.w * v.w;
        }
        red[t] = (ac.x + ac.y) + (ac.z + ac.w);
        __syncthreads();
        if (t < 128) {
            float nrm = sqrtf(red[2 * t] + red[2 * t + 1]);
            if (t < 64) nA[t] = nrm; else nB[t - 64] = nrm;
        }
        __syncthreads();
    }
    int ti = t >> 4, tj = t & 15;
    float acc[4][4];
#pragma unroll
    for (int a = 0; a < 4; a++)
#pragma unroll
        for (int c = 0; c < 4; c++) acc[a][c] = 0.f;
    int sr = t >> 2, sc4 = t & 3;
    const float* arow = hb + (size_t)(2 * (i0 + sr)) * DD;
    const float* brow = hb + (size_t)(2 * (j0 + sr) + 1) * DD;
    float inA = nA[sr], inB = nB[sr];
    float4 a4 = ((const float4*)arow)[sc4];          // prefetch step 0
    float4 b4 = ((const float4*)brow)[sc4];
    a4.x /= inA; a4.y /= inA; a4.z /= inA; a4.w /= inA;
    b4.x /= inB; b4.y /= inB; b4.z /= inB; b4.w /= inB;
    for (int s = 0; s < 48; s++) {
        __syncthreads();
        *(float4*)&As[sr][4 * sc4] = a4;
        BsT[4 * sc4 + 0][sr] = b4.x;
        BsT[4 * sc4 + 1][sr] = b4.y;
        BsT[4 * sc4 + 2][sr] = b4.z;
        BsT[4 * sc4 + 3][sr] = b4.w;
        __syncthreads();
        if (s + 1 < 48) {
            int d0 = (s + 1) * 16;
            a4 = ((const float4*)(arow + d0))[sc4];
            b4 = ((const float4*)(brow + d0))[sc4];
            a4.x /= inA; a4.y /= inA; a4.z /= inA; a4.w /= inA;
            b4.x /= inB; b4.y /= inB; b4.z /= inB; b4.w /= inB;
        }
#pragma unroll
        for (int c4 = 0; c4 < 4; c4++) {
            float4 av[4], bk4[4];
#pragma unroll
            for (int a = 0; a < 4; a++) av[a] = *(const float4*)&As[ti * 4 + a][4 * c4];
#pragma unroll
            for (int k = 0; k < 4; k++) bk4[k] = *(const float4*)&BsT[4 * c4 + k][4 * tj];
#pragma unroll
            for (int k = 0; k < 4; k++) {
#pragma unroll
                for (int a = 0; a < 4; a++) {
                    float ak = ((const float*)&av[a])[k];
#pragma unroll
                    for (int c = 0; c < 4; c++)
                        acc[a][c] += ak * ((const float*)&bk4[k])[c];
                }
            }
        }
    }
#pragma unroll
    for (int a = 0; a < 4; a++) {
        unsigned long long bp = 0ULL;
#pragma unroll
        for (int c = 0; c < 4; c++) {
            int jg = j0 + tj * 4 + c;
            unsigned u = __float_as_uint(acc[a][c]);
            u = (u & 0x80000000u) ? ~u : (u | 0x80000000u);
            unsigned long long pk = ((unsigned long long)u << 32) | (unsigned long long)(255 - jg);
            if (pk > bp) bp = pk;
        }
        cand[ti * 4 + a][tj] = bp;
    }
    __syncthreads();
    if (t < 64) {
        unsigned long long m = cand[t][0];
#pragma unroll
        for (int c2 = 1; c2 < 16; c2++) { unsigned long long v = cand[t][c2]; if (v > m) m = v; }
        g_nodep_part[((size_t)b * HALF + i0 + t) * 4 + jt] = m;
    }
}

// ---------------- K_seledge: sel blocks 0..15 + W2 blocks 16..111 -----------
__global__ void k_seledge(const float* __restrict__ Wk, const float* __restrict__ bk) {
    int blk = blockIdx.x, t = threadIdx.x;
    __shared__ float v[LL];
    __shared__ int pos[LL];
    __shared__ float nm[HALF];
    __shared__ int   ni[HALF];
    __shared__ __align__(16) float qsl[HD];

    if (blk >= BB) {
        // ---- W2[b][h][d] = Wk_h[d,:] . q_h  (per-d order identical) --------
        int wb = blk - BB;
        int b = wb / NH2, h = wb % NH2;
        if (t < HD) qsl[t] = g_q[b * UDIM + h * HD + t];
        __syncthreads();
        if (t < 384) {
#pragma unroll
            for (int rep = 0; rep < 2; rep++) {
                int d = t + rep * 384;
                const float4* wrow = (const float4*)(Wk + (size_t)d * UDIM + h * HD);
                const float4* q4 = (const float4*)qsl;
                float4 s4 = {0.f, 0.f, 0.f, 0.f};
#pragma unroll
                for (int u4 = 0; u4 < 16; u4++) {
                    float4 w = wrow[u4], q = q4[u4];
                    s4.x += q.x * w.x; s4.y += q.y * w.y; s4.z += q.z * w.z; s4.w += q.w * w.w;
                }
                g_w2[((size_t)b * NH2 + h) * DD + d] = (s4.x + s4.y) + (s4.z + s4.w);
            }
        }
        if (t == 0) {
            float a = 0.f;
            for (int u = 0; u < HD; u++) a += qsl[u] * bk[h * HD + u];
            g_qbk[b * NH2 + h] = a;
        }
        return;
    }

    int b = blk;
    float imp = 0.f;
    for (int p = 0; p < NHEAD * 4; p++)
        imp += g_colsum_part[((size_t)b * NHEAD * 4 + p) * LL + t];
    v[t] = imp;
    __syncthreads();
    int cnt = 0;
    for (int k = 0; k < LL; k++) {
        float vk = v[k];
        cnt += (vk > imp) || (vk == imp && k < t);
    }
    int notp = (cnt >= KPRES) ? 1 : 0;
    pos[t] = notp;
    __syncthreads();
    for (int s = 1; s < LL; s <<= 1) {
        int add = (t >= s) ? pos[t - s] : 0;
        __syncthreads();
        pos[t] += add;
        __syncthreads();
    }
    if (notp) g_unp[b * RCNT + pos[t] - 1] = t;
    if (t < HALF) {
        unsigned long long p = g_nodep_part[((size_t)b * HALF + t) * 4 + 0];
#pragma unroll
        for (int q = 1; q < 4; q++) {
            unsigned long long w = g_nodep_part[((size_t)b * HALF + t) * 4 + q];
            if (w > p) p = w;
        }
        unsigned u = (unsigned)(p >> 32);
        unsigned bits = (u & 0x80000000u) ? (u & 0x7FFFFFFFu) : ~u;
        nm[t] = __uint_as_float(bits);
        ni[t] = 255 - (int)(p & 0xFFFFFFFFu);
    }
    __syncthreads();
    if (t < HALF) {
        float vv = nm[t];
        int cnt2 = 0;
        for (int k = 0; k < HALF; k++) {
            float vk = nm[k];
            cnt2 += (vk > vv) || (vk == vv && k < t);
        }
        if (cnt2 < RCNT) {
            g_srctok[b * RCNT + cnt2] = t;
            g_srcdst[b * RCNT + cnt2] = ni[t];
        } else {
            g_unm[b * RCNT + (cnt2 - RCNT)] = 2 * t;
        }
    }
}

// ---------------- K_attn: per-(b,h) attn chain (blocks 0..95) ---------------
// ----------------        + output rows 0..384 (blocks 96..)    --------------
// One head per block (6x less serial depth, 6x more blocks than round-3);
// per-element FP chains identical to the round-3 passing kernel.
// Row blocks depend only on k_seledge, so they fill the GPU while the 96
// attn blocks ride out their load-latency chains.
__global__ void k_attn(const float* __restrict__ hs,
                       const float* __restrict__ Wv, const float* __restrict__ bv,
                       float* __restrict__ out) {
    int blk = blockIdx.x;
    int t = threadIdx.x;
    __shared__ __align__(16) float w2s[DD];
    __shared__ __align__(16) float hbars[DD];
    __shared__ int   toks[RCNT];
    __shared__ float att[RCNT];
    __shared__ float red[256];
    __shared__ float pm[4];
    __shared__ float qbkS;
    __shared__ int ss[RCNT], sd[RCNT];

    if (blk < BB * NH2) {
        int b = blk / NH2, h = blk % NH2;
        const float* hb = hs + (size_t)b * LL * DD;
        if (t < RCNT) toks[t] = g_unp[b * RCNT + t];
        for (int d = t; d < DD; d += 256) w2s[d] = g_w2[((size_t)b * NH2 + h) * DD + d];
        if (t == 0) qbkS = g_qbk[b * NH2 + h];
        __syncthreads();
        // --- logits: 2 threads per token, half a row each (round-3 chain) ---
        {
            int tok = t >> 1, half = t & 1;
            const float4* hr4 = (const float4*)(hb + (size_t)toks[tok] * DD) + half * 96;
            const float4* wk4 = (const float4*)w2s + half * 96;
            float4 s4 = {0.f, 0.f, 0.f, 0.f};
            for (int d4 = 0; d4 < 96; d4++) {
                float4 w = wk4[d4], x = hr4[d4];
                s4.x += w.x * x.x; s4.y += w.y * x.y; s4.z += w.z * x.z; s4.w += w.w * x.w;
            }
            red[t] = (s4.x + s4.y) + (s4.z + s4.w);
        }
        __syncthreads();
        float lg = -1e30f;
        if (t < RCNT) lg = (qbkS + red[2 * t] + red[2 * t + 1]) * 0.125f;
        // --- softmax (verbatim round-3 body) ---
        float m = lg;
#pragma unroll
        for (int off = 32; off >= 1; off >>= 1) m = fmaxf(m, __shfl_xor(m, off, 64));
        if ((t & 63) == 0) pm[t >> 6] = m;
        __syncthreads();
        float mx = fmaxf(pm[0], pm[1]);
        float e = (t < RCNT) ? expf(lg - mx) : 0.f;
        float sume = e;
#pragma unroll
        for (int off = 32; off >= 1; off >>= 1) sume += __shfl_xor(sume, off, 64);
        __syncthreads();
        if ((t & 63) == 0) pm[t >> 6] = sume;
        __syncthreads();
        float inv = 1.f / (pm[0] + pm[1]);
        if (t < RCNT) att[t] = e * inv;
        __syncthreads();
        // --- hbar = sum_tok att * H_tok (ascending tok, round-3 chain) ---
        if (t < DD / 4) {
            float4 a = {0.f, 0.f, 0.f, 0.f};
            for (int s2 = 0; s2 < RCNT; s2++) {
                float4 x = ((const float4*)(hb + (size_t)toks[s2] * DD))[t];
                float w = att[s2];
                a.x += w * x.x; a.y += w * x.y; a.z += w * x.z; a.w += w * x.w;
            }
            *(float4*)&hbars[4 * t] = a;
        }
        __syncthreads();
        // --- ctx = hbar @ Wv_h + bv (4 partials of 192, round-3 chain) ---
        {
            int u = t & 63, part = t >> 6;
            float a = 0.f;
            for (int d = part * 192; d < part * 192 + 192; d++)
                a += hbars[d] * Wv[(size_t)d * UDIM + h * HD + u];
            red[t] = a;
            __syncthreads();
            if (t < HD)
                g_ctx[b * UDIM + h * HD + t] =
                    bv[h * HD + t] + red[t] + red[t + 64] + red[t + 128] + red[t + 192];
        }
        return;
    }

    // ================= output rows 0..384 (copy / unm / merge) ==============
    int rblk = blk - BB * NH2;
    int row = rblk % 385, b = rblk / 385;
    float4* o4 = (float4*)(out + ((size_t)b * 386 + row) * DD);
    if (row == 0) {
        if (t < 192) {
            const float4* s4 = (const float4*)(hs + (size_t)b * LL * DD);
            o4[t] = s4[t];
        }
    } else if (row <= RCNT) {
        int tok = g_unm[b * RCNT + row - 1];
        if (t < 192) {
            const float4* s4 = (const float4*)(hs + ((size_t)b * LL + tok) * DD);
            o4[t] = s4[t];
        }
    } else {
        int j = row - 1 - RCNT;
        if (t < RCNT) { ss[t] = g_srctok[b * RCNT + t]; sd[t] = g_srcdst[b * RCNT + t]; }
        __syncthreads();
        if (t < 192) {
            float4 acc = ((const float4*)(hs + ((size_t)b * LL + 2 * j + 1) * DD))[t];
            float cnt = 1.f;
            for (int s2 = 0; s2 < RCNT; s2++) {   // ascending rank == np.add.at order
                if (sd[s2] == j) {
                    float4 v = ((const float4*)(hs + ((size_t)b * LL + 2 * ss[s2]) * DD))[t];
                    acc.x += v.x; acc.y += v.y; acc.z += v.z; acc.w += v.w;
                    cnt += 1.f;
                }
            }
            float4 r;
            r.x = acc.x / cnt; r.y = acc.y / cnt; r.z = acc.z / cnt; r.w = acc.w / cnt;
            o4[t] = r;
        }
    }
}

// ---------------- K_newtok: row 385 per batch, 4 blocks/batch ---------------
// Same serial-u chain as round-3 (bit-identical per output element).
__global__ void k_newtok(const float* __restrict__ Wo, const float* __restrict__ bo,
                         float* __restrict__ out) {
    int b = blockIdx.x >> 2, q = blockIdx.x & 3;
    int t = threadIdx.x;
    __shared__ float c[UDIM];
    c[t] = g_ctx[b * UDIM + t];
    c[t + 192] = g_ctx[b * UDIM + t + 192];
    __syncthreads();
    int dd = q * 192 + t;
    float acc = bo[dd];
    for (int u = 0; u < UDIM; u++)
        acc += c[u] * Wo[(size_t)u * DD + dd];
    out[((size_t)b * 386 + 385) * DD + dd] = acc;
}

extern "C" void kernel_launch(void* const* d_in, const int* in_sizes, int n_in,
                              void* d_out, int out_size, void* d_ws, size_t ws_size,
                              hipStream_t stream) {
    const float* hs = (const float*)d_in[0];
    const float* sc = (const float*)d_in[1];
    const float* Wq = (const float*)d_in[2];
    const float* bq = (const float*)d_in[3];
    const float* Wk = (const float*)d_in[4];
    const float* bk = (const float*)d_in[5];
    const float* Wv = (const float*)d_in[6];
    const float* bv = (const float*)d_in[7];
    const float* Wo = (const float*)d_in[8];
    const float* bo = (const float*)d_in[9];
    float* out = (float*)d_out;
    (void)d_ws; (void)ws_size;

    k_main<<<256 + BB * NHEAD * 4 + BB * NH2, 256, 0, stream>>>(sc, hs, Wq, bq);
    k_seledge<<<BB + BB * NH2, 512, 0, stream>>>(Wk, bk);
    k_attn<<<BB * NH2 + BB * 385, 256, 0, stream>>>(hs, Wv, bv, out);
    k_newtok<<<BB * 4, 192, 0, stream>>>(Wo, bo, out);
}

// Round 5
// 449.681 us; speedup vs baseline: 1.6769x; 1.0038x over previous
//
#include <hip/hip_runtime.h>

#define BB 16
#define LL 512
#define DD 768
#define NHEAD 12
#define HALF 256      // L/2
#define KPRES 384
#define RCNT 128      // L - K
#define UDIM 384
#define NH2 6
#define HD 64

// ---- module-scope scratch (deterministic, no atomics) ----------------------
__device__ float              g_colsum_part[BB * NHEAD * 4 * LL]; // 1.57 MB
__device__ unsigned long long g_nodep_part[BB * HALF * 4];        // 128 KB
__device__ int g_unm[BB * RCNT];
__device__ int g_srctok[BB * RCNT];
__device__ int g_srcdst[BB * RCNT];
__device__ int g_unp[BB * RCNT];
__device__ float g_q[BB * UDIM];        // q per (b, h*64+u)
__device__ float g_w2[BB * NH2 * DD];   // W2[b][h][d] = Wk_h[d,:] . q_h
__device__ float g_qbk[BB * NH2];       // q_h . bk_h
__device__ float g_ctx[BB * UDIM];      // ctx per (b, h*64+u)

// ---------------- K_main: sim tiles (0..511, 32x64 each) --------------------
// ----------------         + colsum (512..1279) + q-proj (1280..1375) -------
// 32x64 sim tiles double the sim-phase block count vs round-4 (2 blocks/CU
// during the tail instead of 1 -> 4 waves/SIMD instead of 1). j-tile width,
// per-thread 4-col groups, per-pair k-chains, and norm chains are unchanged
// => bit-identical selections.
__global__ void k_main(const float* __restrict__ sc, const float* __restrict__ hs,
                       const float* __restrict__ Wq, const float* __restrict__ bq) {
    __shared__ __align__(16) float As[32][20];   // rows 80 B apart
    __shared__ __align__(16) float BsT[16][68];  // [k][col], pad 68
    __shared__ float nA[32], nB[64];
    __shared__ unsigned long long cand[32][16];
    __shared__ float red[256];
    __shared__ __align__(16) float4 smc[256];    // colsum parity combine
    __shared__ float h0q[DD];
    int blk = blockIdx.x;
    int t = threadIdx.x;

    if (blk >= 1280) {
        // ---- q projection for (b,h): 4 partials of 192, round-0 FP order ---
        int qb = blk - 1280;
        int b = qb / NH2, h = qb % NH2;
        const float* hb = hs + (size_t)b * LL * DD;
        for (int d = t; d < DD; d += 256) h0q[d] = hb[d];
        __syncthreads();
        int u = t & 63, part = t >> 6;
        float a = 0.f;
        for (int d = part * 192; d < part * 192 + 192; d++)
            a += h0q[d] * Wq[(size_t)d * UDIM + h * HD + u];
        red[t] = a;
        __syncthreads();
        if (t < HD)
            g_q[b * UDIM + h * HD + t] =
                bq[h * HD + t] + red[t] + red[t + 64] + red[t + 128] + red[t + 192];
        return;
    }

    if (blk >= 512) {
        // ---- colsum partial (b,h,128-row chunk), diag excluded, float4 ----
        int cb = blk - 512;                // 0..767
        int ic = cb & 3;
        int bh = cb >> 2;                  // b*NHEAD + h
        const float* base = sc + (size_t)bh * LL * LL;
        int i0 = ic * 128;
        int p = t >> 7;                    // row parity within chunk
        int s = t & 127;                   // float4 slot -> cols 4s..4s+3
        float4 acc = {0.f, 0.f, 0.f, 0.f};
#pragma unroll 8
        for (int i = 0; i < 64; i++) {     // ascending i within parity: fixed order
            float4 v = ((const float4*)(base + (size_t)(i0 + 2 * i + p) * LL))[s];
            acc.x += v.x; acc.y += v.y; acc.z += v.z; acc.w += v.w;
        }
#pragma unroll
        for (int c = 0; c < 4; c++) {      // subtract owned diagonals
            int cj = 4 * s + c;
            if (cj >= i0 && cj < i0 + 128 && (cj & 1) == p) {
                float d = base[(size_t)cj * LL + cj];
                if (c == 0) acc.x -= d; else if (c == 1) acc.y -= d;
                else if (c == 2) acc.z -= d; else acc.w -= d;
            }
        }
        smc[t] = acc;
        __syncthreads();
        if (t < 128) {                     // partial = evens-sum + odds-sum
            float4 e = smc[t], o = smc[t + 128];
            float4 r;
            r.x = e.x + o.x; r.y = e.y + o.y; r.z = e.z + o.z; r.w = e.w + o.w;
            ((float4*)(g_colsum_part + (size_t)cb * LL))[t] = r;
        }
        return;
    }

    // ---- sim tile + fused row-argmax (32 even-rows x 64 odd-cols) ----------
    int b = blk >> 5;
    int rem = blk & 31;
    int it = rem >> 2, jt = rem & 3;       // 8 i-tiles x 4 j-tiles
    int i0 = it * 32, j0 = jt * 64;
    const float* hb = hs + (size_t)b * LL * DD;
    // norms prologue: 2 threads per row (per-row chain identical to round-4)
    {
        if (t < 192) {
            int rl = t >> 1, hf = t & 1;
            int grow = (rl < 32) ? 2 * (i0 + rl) : 2 * (j0 + rl - 32) + 1;
            const float4* rp = (const float4*)(hb + (size_t)grow * DD) + hf * 96;
            float4 ac = {0.f, 0.f, 0.f, 0.f};
#pragma unroll 4
            for (int q = 0; q < 96; q++) {
                float4 v = rp[q];
                ac.x += v.x * v.x; ac.y += v.y * v.y; ac.z += v.z * v.z; ac.w += v.w * v.w;
            }
            red[t] = (ac.x + ac.y) + (ac.z + ac.w);
        }
        __syncthreads();
        if (t < 96) {
            float nrm = sqrtf(red[2 * t] + red[2 * t + 1]);
            if (t < 32) nA[t] = nrm; else nB[t - 32] = nrm;
        }
        __syncthreads();
    }
    int ti = t >> 4, tj = t & 15;          // ti 0..15 -> rows ti*2+a; tj*4+c cols
    float acc[2][4];
#pragma unroll
    for (int a = 0; a < 2; a++)
#pragma unroll
        for (int c = 0; c < 4; c++) acc[a][c] = 0.f;
    // staging: all 256 threads stage one B float4 (64 rows x 4 slots);
    // threads 0..127 additionally stage one A float4 (32 rows x 4 slots)
    int sr = t >> 2, sc4 = t & 3;          // B row 0..63, slot
    int srA = (t & 127) >> 2;              // A row 0..31 (threads <128)
    const float* brow = hb + (size_t)(2 * (j0 + sr) + 1) * DD;
    const float* arow = hb + (size_t)(2 * (i0 + srA)) * DD;
    float inB = nB[sr];
    float inA = (t < 128) ? nA[srA] : 1.f;
    float4 b4 = ((const float4*)brow)[sc4];          // prefetch step 0
    b4.x /= inB; b4.y /= inB; b4.z /= inB; b4.w /= inB;
    float4 a4 = {0.f, 0.f, 0.f, 0.f};
    if (t < 128) {
        a4 = ((const float4*)arow)[sc4];
        a4.x /= inA; a4.y /= inA; a4.z /= inA; a4.w /= inA;
    }
    for (int s = 0; s < 48; s++) {
        __syncthreads();
        BsT[4 * sc4 + 0][sr] = b4.x;
        BsT[4 * sc4 + 1][sr] = b4.y;
        BsT[4 * sc4 + 2][sr] = b4.z;
        BsT[4 * sc4 + 3][sr] = b4.w;
        if (t < 128) *(float4*)&As[srA][4 * sc4] = a4;
        __syncthreads();
        if (s + 1 < 48) {                            // prefetch + divide next
            int d0 = (s + 1) * 16;
            b4 = ((const float4*)(brow + d0))[sc4];
            b4.x /= inB; b4.y /= inB; b4.z /= inB; b4.w /= inB;
            if (t < 128) {
                a4 = ((const float4*)(arow + d0))[sc4];
                a4.x /= inA; a4.y /= inA; a4.z /= inA; a4.w /= inA;
            }
        }
#pragma unroll
        for (int c4 = 0; c4 < 4; c4++) {
            float4 av[2], bk4[4];
#pragma unroll
            for (int a = 0; a < 2; a++) av[a] = *(const float4*)&As[ti * 2 + a][4 * c4];
#pragma unroll
            for (int k = 0; k < 4; k++) bk4[k] = *(const float4*)&BsT[4 * c4 + k][4 * tj];
#pragma unroll
            for (int k = 0; k < 4; k++) {            // k ascending: same fp order
#pragma unroll
                for (int a = 0; a < 2; a++) {
                    float ak = ((const float*)&av[a])[k];
#pragma unroll
                    for (int c = 0; c < 4; c++)
                        acc[a][c] += ak * ((const float*)&bk4[k])[c];
                }
            }
        }
    }
    // pack (sim, smaller-j-wins) into sortable u64; per-thread best over 4 cols
#pragma unroll
    for (int a = 0; a < 2; a++) {
        unsigned long long bp = 0ULL;
#pragma unroll
        for (int c = 0; c < 4; c++) {
            int jg = j0 + tj * 4 + c;
            unsigned u = __float_as_uint(acc[a][c]);
            u = (u & 0x80000000u) ? ~u : (u | 0x80000000u);
            unsigned long long pk = ((unsigned long long)u << 32) | (unsigned long long)(255 - jg);
            if (pk > bp) bp = pk;
        }
        cand[ti * 2 + a][tj] = bp;
    }
    __syncthreads();
    if (t < 32) {
        unsigned long long m = cand[t][0];
#pragma unroll
        for (int c2 = 1; c2 < 16; c2++) { unsigned long long v = cand[t][c2]; if (v > m) m = v; }
        g_nodep_part[((size_t)b * HALF + i0 + t) * 4 + jt] = m;
    }
}

// ---------------- K_seledge: sel blocks 0..15 + W2 blocks 16..111 -----------
__global__ void k_seledge(const float* __restrict__ Wk, const float* __restrict__ bk) {
    int blk = blockIdx.x, t = threadIdx.x;
    __shared__ float v[LL];
    __shared__ int pos[LL];
    __shared__ float nm[HALF];
    __shared__ int   ni[HALF];
    __shared__ __align__(16) float qsl[HD];

    if (blk >= BB) {
        // ---- W2[b][h][d] = Wk_h[d,:] . q_h  (per-d order identical) --------
        int wb = blk - BB;
        int b = wb / NH2, h = wb % NH2;
        if (t < HD) qsl[t] = g_q[b * UDIM + h * HD + t];
        __syncthreads();
        if (t < 384) {
#pragma unroll
            for (int rep = 0; rep < 2; rep++) {
                int d = t + rep * 384;
                const float4* wrow = (const float4*)(Wk + (size_t)d * UDIM + h * HD);
                const float4* q4 = (const float4*)qsl;
                float4 s4 = {0.f, 0.f, 0.f, 0.f};
#pragma unroll
                for (int u4 = 0; u4 < 16; u4++) {
                    float4 w = wrow[u4], q = q4[u4];
                    s4.x += q.x * w.x; s4.y += q.y * w.y; s4.z += q.z * w.z; s4.w += q.w * w.w;
                }
                g_w2[((size_t)b * NH2 + h) * DD + d] = (s4.x + s4.y) + (s4.z + s4.w);
            }
        }
        if (t == 0) {
            float a = 0.f;
            for (int u = 0; u < HD; u++) a += qsl[u] * bk[h * HD + u];
            g_qbk[b * NH2 + h] = a;
        }
        return;
    }

    int b = blk;
    float imp = 0.f;
    for (int p = 0; p < NHEAD * 4; p++)
        imp += g_colsum_part[((size_t)b * NHEAD * 4 + p) * LL + t];
    v[t] = imp;
    __syncthreads();
    int cnt = 0;
    for (int k = 0; k < LL; k++) {
        float vk = v[k];
        cnt += (vk > imp) || (vk == imp && k < t);
    }
    int notp = (cnt >= KPRES) ? 1 : 0;
    pos[t] = notp;
    __syncthreads();
    for (int s = 1; s < LL; s <<= 1) {
        int add = (t >= s) ? pos[t - s] : 0;
        __syncthreads();
        pos[t] += add;
        __syncthreads();
    }
    if (notp) g_unp[b * RCNT + pos[t] - 1] = t;
    if (t < HALF) {
        unsigned long long p = g_nodep_part[((size_t)b * HALF + t) * 4 + 0];
#pragma unroll
        for (int q = 1; q < 4; q++) {
            unsigned long long w = g_nodep_part[((size_t)b * HALF + t) * 4 + q];
            if (w > p) p = w;
        }
        unsigned u = (unsigned)(p >> 32);
        unsigned bits = (u & 0x80000000u) ? (u & 0x7FFFFFFFu) : ~u;
        nm[t] = __uint_as_float(bits);
        ni[t] = 255 - (int)(p & 0xFFFFFFFFu);
    }
    __syncthreads();
    if (t < HALF) {
        float vv = nm[t];
        int cnt2 = 0;
        for (int k = 0; k < HALF; k++) {
            float vk = nm[k];
            cnt2 += (vk > vv) || (vk == vv && k < t);
        }
        if (cnt2 < RCNT) {
            g_srctok[b * RCNT + cnt2] = t;
            g_srcdst[b * RCNT + cnt2] = ni[t];
        } else {
            g_unm[b * RCNT + (cnt2 - RCNT)] = 2 * t;
        }
    }
}

// ---------------- K_attn: per-(b,h) attn chain (blocks 0..95) ---------------
// ----------------        + output rows 0..384 (blocks 96..)    --------------
__global__ void k_attn(const float* __restrict__ hs,
                       const float* __restrict__ Wv, const float* __restrict__ bv,
                       float* __restrict__ out) {
    int blk = blockIdx.x;
    int t = threadIdx.x;
    __shared__ __align__(16) float w2s[DD];
    __shared__ __align__(16) float hbars[DD];
    __shared__ int   toks[RCNT];
    __shared__ float att[RCNT];
    __shared__ float red[256];
    __shared__ float pm[4];
    __shared__ float qbkS;
    __shared__ int ss[RCNT], sd[RCNT];

    if (blk < BB * NH2) {
        int b = blk / NH2, h = blk % NH2;
        const float* hb = hs + (size_t)b * LL * DD;
        if (t < RCNT) toks[t] = g_unp[b * RCNT + t];
        for (int d = t; d < DD; d += 256) w2s[d] = g_w2[((size_t)b * NH2 + h) * DD + d];
        if (t == 0) qbkS = g_qbk[b * NH2 + h];
        __syncthreads();
        // --- logits: 2 threads per token, half a row each ---
        {
            int tok = t >> 1, half = t & 1;
            const float4* hr4 = (const float4*)(hb + (size_t)toks[tok] * DD) + half * 96;
            const float4* wk4 = (const float4*)w2s + half * 96;
            float4 s4 = {0.f, 0.f, 0.f, 0.f};
            for (int d4 = 0; d4 < 96; d4++) {
                float4 w = wk4[d4], x = hr4[d4];
                s4.x += w.x * x.x; s4.y += w.y * x.y; s4.z += w.z * x.z; s4.w += w.w * x.w;
            }
            red[t] = (s4.x + s4.y) + (s4.z + s4.w);
        }
        __syncthreads();
        float lg = -1e30f;
        if (t < RCNT) lg = (qbkS + red[2 * t] + red[2 * t + 1]) * 0.125f;
        // --- softmax ---
        float m = lg;
#pragma unroll
        for (int off = 32; off >= 1; off >>= 1) m = fmaxf(m, __shfl_xor(m, off, 64));
        if ((t & 63) == 0) pm[t >> 6] = m;
        __syncthreads();
        float mx = fmaxf(pm[0], pm[1]);
        float e = (t < RCNT) ? expf(lg - mx) : 0.f;
        float sume = e;
#pragma unroll
        for (int off = 32; off >= 1; off >>= 1) sume += __shfl_xor(sume, off, 64);
        __syncthreads();
        if ((t & 63) == 0) pm[t >> 6] = sume;
        __syncthreads();
        float inv = 1.f / (pm[0] + pm[1]);
        if (t < RCNT) att[t] = e * inv;
        __syncthreads();
        // --- hbar = sum_tok att * H_tok (ascending tok) ---
        if (t < DD / 4) {
            float4 a = {0.f, 0.f, 0.f, 0.f};
            for (int s2 = 0; s2 < RCNT; s2++) {
                float4 x = ((const float4*)(hb + (size_t)toks[s2] * DD))[t];
                float w = att[s2];
                a.x += w * x.x; a.y += w * x.y; a.z += w * x.z; a.w += w * x.w;
            }
            *(float4*)&hbars[4 * t] = a;
        }
        __syncthreads();
        // --- ctx = hbar @ Wv_h + bv (4 partials of 192) ---
        {
            int u = t & 63, part = t >> 6;
            float a = 0.f;
            for (int d = part * 192; d < part * 192 + 192; d++)
                a += hbars[d] * Wv[(size_t)d * UDIM + h * HD + u];
            red[t] = a;
            __syncthreads();
            if (t < HD)
                g_ctx[b * UDIM + h * HD + t] =
                    bv[h * HD + t] + red[t] + red[t + 64] + red[t + 128] + red[t + 192];
        }
        return;
    }

    // ================= output rows 0..384 (copy / unm / merge) ==============
    int rblk = blk - BB * NH2;
    int row = rblk % 385, b = rblk / 385;
    float4* o4 = (float4*)(out + ((size_t)b * 386 + row) * DD);
    if (row == 0) {
        if (t < 192) {
            const float4* s4 = (const float4*)(hs + (size_t)b * LL * DD);
            o4[t] = s4[t];
        }
    } else if (row <= RCNT) {
        int tok = g_unm[b * RCNT + row - 1];
        if (t < 192) {
            const float4* s4 = (const float4*)(hs + ((size_t)b * LL + tok) * DD);
            o4[t] = s4[t];
        }
    } else {
        int j = row - 1 - RCNT;
        if (t < RCNT) { ss[t] = g_srctok[b * RCNT + t]; sd[t] = g_srcdst[b * RCNT + t]; }
        __syncthreads();
        if (t < 192) {
            float4 acc = ((const float4*)(hs + ((size_t)b * LL + 2 * j + 1) * DD))[t];
            float cnt = 1.f;
            for (int s2 = 0; s2 < RCNT; s2++) {   // ascending rank == np.add.at order
                if (sd[s2] == j) {
                    float4 v = ((const float4*)(hs + ((size_t)b * LL + 2 * ss[s2]) * DD))[t];
                    acc.x += v.x; acc.y += v.y; acc.z += v.z; acc.w += v.w;
                    cnt += 1.f;
                }
            }
            float4 r;
            r.x = acc.x / cnt; r.y = acc.y / cnt; r.z = acc.z / cnt; r.w = acc.w / cnt;
            o4[t] = r;
        }
    }
}

// ---------------- K_newtok: row 385 per batch, 4 blocks/batch ---------------
__global__ void k_newtok(const float* __restrict__ Wo, const float* __restrict__ bo,
                         float* __restrict__ out) {
    int b = blockIdx.x >> 2, q = blockIdx.x & 3;
    int t = threadIdx.x;
    __shared__ float c[UDIM];
    c[t] = g_ctx[b * UDIM + t];
    c[t + 192] = g_ctx[b * UDIM + t + 192];
    __syncthreads();
    int dd = q * 192 + t;
    float acc = bo[dd];
    for (int u = 0; u < UDIM; u++)
        acc += c[u] * Wo[(size_t)u * DD + dd];
    out[((size_t)b * 386 + 385) * DD + dd] = acc;
}

extern "C" void kernel_launch(void* const* d_in, const int* in_sizes, int n_in,
                              void* d_out, int out_size, void* d_ws, size_t ws_size,
                              hipStream_t stream) {
    const float* hs = (const float*)d_in[0];
    const float* sc = (const float*)d_in[1];
    const float* Wq = (const float*)d_in[2];
    const float* bq = (const float*)d_in[3];
    const float* Wk = (const float*)d_in[4];
    const float* bk = (const float*)d_in[5];
    const float* Wv = (const float*)d_in[6];
    const float* bv = (const float*)d_in[7];
    const float* Wo = (const float*)d_in[8];
    const float* bo = (const float*)d_in[9];
    float* out = (float*)d_out;
    (void)d_ws; (void)ws_size;

    k_main<<<512 + BB * NHEAD * 4 + BB * NH2, 256, 0, stream>>>(sc, hs, Wq, bq);
    k_seledge<<<BB + BB * NH2, 512, 0, stream>>>(Wk, bk);
    k_attn<<<BB * NH2 + BB * 385, 256, 0, stream>>>(hs, Wv, bv, out);
    k_newtok<<<BB * 4, 192, 0, stream>>>(Wo, bo, out);
}

// Round 6
// 436.930 us; speedup vs baseline: 1.7258x; 1.0292x over previous
//
#include <hip/hip_runtime.h>

#define BB 16
#define LL 512
#define DD 768
#define NHEAD 12
#define HALF 256      // L/2
#define KPRES 384
#define RCNT 128      // L - K
#define UDIM 384
#define NH2 6
#define HD 64

// ---- module-scope scratch (deterministic, no atomics) ----------------------
__device__ float              g_colsum_part[BB * NHEAD * 4 * LL]; // 1.57 MB
__device__ unsigned long long g_nodep_part[BB * HALF * 4];        // 128 KB
__device__ int g_unm[BB * RCNT];
__device__ int g_srctok[BB * RCNT];
__device__ int g_srcdst[BB * RCNT];
__device__ int g_unp[BB * RCNT];
__device__ float g_q[BB * UDIM];        // q per (b, h*64+u)
__device__ float g_w2[BB * NH2 * DD];   // W2[b][h][d] = Wk_h[d,:] . q_h
__device__ float g_qbk[BB * NH2];       // q_h . bk_h
__device__ float g_ctx[BB * UDIM];      // ctx per (b, h*64+u)

// ---------------- K_main: sim tiles (0..511, 32x64, BK=32) ------------------
// ----------------         + colsum (512..1279) + q-proj (1280..1375) -------
// R5 post-mortem: sim phase is per-block serial-latency bound (48 steps x
// 2 barriers); more blocks/CU didn't help. BK=32 halves the step count
// (24 steps, 48 barriers) and doubles FMA per step. k order 32s+4c4+k is
// still strictly ascending => bit-identical dot products.
__global__ void k_main(const float* __restrict__ sc, const float* __restrict__ hs,
                       const float* __restrict__ Wq, const float* __restrict__ bq) {
    __shared__ __align__(16) float As[32][36];   // rows 144 B apart
    __shared__ __align__(16) float BsT[32][68];  // [k][col], pad 68
    __shared__ float nA[32], nB[64];
    __shared__ unsigned long long cand[32][16];
    __shared__ float red[256];
    __shared__ __align__(16) float4 smc[256];    // colsum parity combine
    __shared__ float h0q[DD];
    int blk = blockIdx.x;
    int t = threadIdx.x;

    if (blk >= 1280) {
        // ---- q projection for (b,h): 4 partials of 192, round-0 FP order ---
        int qb = blk - 1280;
        int b = qb / NH2, h = qb % NH2;
        const float* hb = hs + (size_t)b * LL * DD;
        for (int d = t; d < DD; d += 256) h0q[d] = hb[d];
        __syncthreads();
        int u = t & 63, part = t >> 6;
        float a = 0.f;
        for (int d = part * 192; d < part * 192 + 192; d++)
            a += h0q[d] * Wq[(size_t)d * UDIM + h * HD + u];
        red[t] = a;
        __syncthreads();
        if (t < HD)
            g_q[b * UDIM + h * HD + t] =
                bq[h * HD + t] + red[t] + red[t + 64] + red[t + 128] + red[t + 192];
        return;
    }

    if (blk >= 512) {
        // ---- colsum partial (b,h,128-row chunk), diag excluded, float4 ----
        int cb = blk - 512;                // 0..767
        int ic = cb & 3;
        int bh = cb >> 2;                  // b*NHEAD + h
        const float* base = sc + (size_t)bh * LL * LL;
        int i0 = ic * 128;
        int p = t >> 7;                    // row parity within chunk
        int s = t & 127;                   // float4 slot -> cols 4s..4s+3
        float4 acc = {0.f, 0.f, 0.f, 0.f};
#pragma unroll 8
        for (int i = 0; i < 64; i++) {     // ascending i within parity: fixed order
            float4 v = ((const float4*)(base + (size_t)(i0 + 2 * i + p) * LL))[s];
            acc.x += v.x; acc.y += v.y; acc.z += v.z; acc.w += v.w;
        }
#pragma unroll
        for (int c = 0; c < 4; c++) {      // subtract owned diagonals
            int cj = 4 * s + c;
            if (cj >= i0 && cj < i0 + 128 && (cj & 1) == p) {
                float d = base[(size_t)cj * LL + cj];
                if (c == 0) acc.x -= d; else if (c == 1) acc.y -= d;
                else if (c == 2) acc.z -= d; else acc.w -= d;
            }
        }
        smc[t] = acc;
        __syncthreads();
        if (t < 128) {                     // partial = evens-sum + odds-sum
            float4 e = smc[t], o = smc[t + 128];
            float4 r;
            r.x = e.x + o.x; r.y = e.y + o.y; r.z = e.z + o.z; r.w = e.w + o.w;
            ((float4*)(g_colsum_part + (size_t)cb * LL))[t] = r;
        }
        return;
    }

    // ---- sim tile + fused row-argmax (32 even-rows x 64 odd-cols, BK=32) ---
    int b = blk >> 5;
    int rem = blk & 31;
    int it = rem >> 2, jt = rem & 3;       // 8 i-tiles x 4 j-tiles
    int i0 = it * 32, j0 = jt * 64;
    const float* hb = hs + (size_t)b * LL * DD;
    // norms prologue: 2 threads per row (per-row chain identical)
    {
        if (t < 192) {
            int rl = t >> 1, hf = t & 1;
            int grow = (rl < 32) ? 2 * (i0 + rl) : 2 * (j0 + rl - 32) + 1;
            const float4* rp = (const float4*)(hb + (size_t)grow * DD) + hf * 96;
            float4 ac = {0.f, 0.f, 0.f, 0.f};
#pragma unroll 4
            for (int q = 0; q < 96; q++) {
                float4 v = rp[q];
                ac.x += v.x * v.x; ac.y += v.y * v.y; ac.z += v.z * v.z; ac.w += v.w * v.w;
            }
            red[t] = (ac.x + ac.y) + (ac.z + ac.w);
        }
        __syncthreads();
        if (t < 96) {
            float nrm = sqrtf(red[2 * t] + red[2 * t + 1]);
            if (t < 32) nA[t] = nrm; else nB[t - 32] = nrm;
        }
        __syncthreads();
    }
    int ti = t >> 4, tj = t & 15;          // ti 0..15 -> rows ti*2+a; cols tj*4+c
    float acc[2][4];
#pragma unroll
    for (int a = 0; a < 2; a++)
#pragma unroll
        for (int c = 0; c < 4; c++) acc[a][c] = 0.f;
    // staging (BK=32): A 32 rows x 8 slots -> 1 float4/thread;
    //                  B 64 rows x 8 slots -> 2 float4/thread (slots s, s+4)
    int sAr = t >> 3, sAs = t & 7;         // A row, float4 slot
    int sBr = t >> 2, sBs = t & 3;         // B row, base slot
    const float* arow = hb + (size_t)(2 * (i0 + sAr)) * DD;
    const float* brow = hb + (size_t)(2 * (j0 + sBr) + 1) * DD;
    float inA = nA[sAr], inB = nB[sBr];
    float4 a4 = ((const float4*)arow)[sAs];          // prefetch step 0
    a4.x /= inA; a4.y /= inA; a4.z /= inA; a4.w /= inA;
    float4 b4a = ((const float4*)brow)[sBs];
    float4 b4b = ((const float4*)brow)[sBs + 4];
    b4a.x /= inB; b4a.y /= inB; b4a.z /= inB; b4a.w /= inB;
    b4b.x /= inB; b4b.y /= inB; b4b.z /= inB; b4b.w /= inB;
    for (int s = 0; s < 24; s++) {
        __syncthreads();
        *(float4*)&As[sAr][4 * sAs] = a4;
        BsT[4 * sBs + 0][sBr] = b4a.x;
        BsT[4 * sBs + 1][sBr] = b4a.y;
        BsT[4 * sBs + 2][sBr] = b4a.z;
        BsT[4 * sBs + 3][sBr] = b4a.w;
        BsT[4 * (sBs + 4) + 0][sBr] = b4b.x;
        BsT[4 * (sBs + 4) + 1][sBr] = b4b.y;
        BsT[4 * (sBs + 4) + 2][sBr] = b4b.z;
        BsT[4 * (sBs + 4) + 3][sBr] = b4b.w;
        __syncthreads();
        if (s + 1 < 24) {                            // prefetch + divide next
            int d4 = (s + 1) * 8;
            a4 = ((const float4*)arow)[d4 + sAs];
            a4.x /= inA; a4.y /= inA; a4.z /= inA; a4.w /= inA;
            b4a = ((const float4*)brow)[d4 + sBs];
            b4b = ((const float4*)brow)[d4 + sBs + 4];
            b4a.x /= inB; b4a.y /= inB; b4a.z /= inB; b4a.w /= inB;
            b4b.x /= inB; b4b.y /= inB; b4b.z /= inB; b4b.w /= inB;
        }
#pragma unroll
        for (int c4 = 0; c4 < 8; c4++) {             // k = 32s + 4*c4 + kk, ascending
            float4 av[2], bk4[4];
#pragma unroll
            for (int a = 0; a < 2; a++) av[a] = *(const float4*)&As[ti * 2 + a][4 * c4];
#pragma unroll
            for (int k = 0; k < 4; k++) bk4[k] = *(const float4*)&BsT[4 * c4 + k][4 * tj];
#pragma unroll
            for (int k = 0; k < 4; k++) {
#pragma unroll
                for (int a = 0; a < 2; a++) {
                    float ak = ((const float*)&av[a])[k];
#pragma unroll
                    for (int c = 0; c < 4; c++)
                        acc[a][c] += ak * ((const float*)&bk4[k])[c];
                }
            }
        }
    }
    // pack (sim, smaller-j-wins) into sortable u64; per-thread best over 4 cols
#pragma unroll
    for (int a = 0; a < 2; a++) {
        unsigned long long bp = 0ULL;
#pragma unroll
        for (int c = 0; c < 4; c++) {
            int jg = j0 + tj * 4 + c;
            unsigned u = __float_as_uint(acc[a][c]);
            u = (u & 0x80000000u) ? ~u : (u | 0x80000000u);
            unsigned long long pk = ((unsigned long long)u << 32) | (unsigned long long)(255 - jg);
            if (pk > bp) bp = pk;
        }
        cand[ti * 2 + a][tj] = bp;
    }
    __syncthreads();
    if (t < 32) {
        unsigned long long m = cand[t][0];
#pragma unroll
        for (int c2 = 1; c2 < 16; c2++) { unsigned long long v = cand[t][c2]; if (v > m) m = v; }
        g_nodep_part[((size_t)b * HALF + i0 + t) * 4 + jt] = m;
    }
}

// ---------------- K_seledge: sel blocks 0..15 + W2 blocks 16..111 -----------
__global__ void k_seledge(const float* __restrict__ Wk, const float* __restrict__ bk) {
    int blk = blockIdx.x, t = threadIdx.x;
    __shared__ float v[LL];
    __shared__ int pos[LL];
    __shared__ float nm[HALF];
    __shared__ int   ni[HALF];
    __shared__ __align__(16) float qsl[HD];

    if (blk >= BB) {
        // ---- W2[b][h][d] = Wk_h[d,:] . q_h  (per-d order identical) --------
        int wb = blk - BB;
        int b = wb / NH2, h = wb % NH2;
        if (t < HD) qsl[t] = g_q[b * UDIM + h * HD + t];
        __syncthreads();
        if (t < 384) {
#pragma unroll
            for (int rep = 0; rep < 2; rep++) {
                int d = t + rep * 384;
                const float4* wrow = (const float4*)(Wk + (size_t)d * UDIM + h * HD);
                const float4* q4 = (const float4*)qsl;
                float4 s4 = {0.f, 0.f, 0.f, 0.f};
#pragma unroll
                for (int u4 = 0; u4 < 16; u4++) {
                    float4 w = wrow[u4], q = q4[u4];
                    s4.x += q.x * w.x; s4.y += q.y * w.y; s4.z += q.z * w.z; s4.w += q.w * w.w;
                }
                g_w2[((size_t)b * NH2 + h) * DD + d] = (s4.x + s4.y) + (s4.z + s4.w);
            }
        }
        if (t == 0) {
            float a = 0.f;
            for (int u = 0; u < HD; u++) a += qsl[u] * bk[h * HD + u];
            g_qbk[b * NH2 + h] = a;
        }
        return;
    }

    int b = blk;
    float imp = 0.f;
    for (int p = 0; p < NHEAD * 4; p++)
        imp += g_colsum_part[((size_t)b * NHEAD * 4 + p) * LL + t];
    v[t] = imp;
    __syncthreads();
    int cnt = 0;
    for (int k = 0; k < LL; k++) {
        float vk = v[k];
        cnt += (vk > imp) || (vk == imp && k < t);
    }
    int notp = (cnt >= KPRES) ? 1 : 0;
    pos[t] = notp;
    __syncthreads();
    for (int s = 1; s < LL; s <<= 1) {
        int add = (t >= s) ? pos[t - s] : 0;
        __syncthreads();
        pos[t] += add;
        __syncthreads();
    }
    if (notp) g_unp[b * RCNT + pos[t] - 1] = t;
    if (t < HALF) {
        unsigned long long p = g_nodep_part[((size_t)b * HALF + t) * 4 + 0];
#pragma unroll
        for (int q = 1; q < 4; q++) {
            unsigned long long w = g_nodep_part[((size_t)b * HALF + t) * 4 + q];
            if (w > p) p = w;
        }
        unsigned u = (unsigned)(p >> 32);
        unsigned bits = (u & 0x80000000u) ? (u & 0x7FFFFFFFu) : ~u;
        nm[t] = __uint_as_float(bits);
        ni[t] = 255 - (int)(p & 0xFFFFFFFFu);
    }
    __syncthreads();
    if (t < HALF) {
        float vv = nm[t];
        int cnt2 = 0;
        for (int k = 0; k < HALF; k++) {
            float vk = nm[k];
            cnt2 += (vk > vv) || (vk == vv && k < t);
        }
        if (cnt2 < RCNT) {
            g_srctok[b * RCNT + cnt2] = t;
            g_srcdst[b * RCNT + cnt2] = ni[t];
        } else {
            g_unm[b * RCNT + (cnt2 - RCNT)] = 2 * t;
        }
    }
}

// ---------------- K_attn: per-(b,h) attn chain (blocks 0..95) ---------------
// ----------------        + output rows 0..384 (blocks 96..)    --------------
__global__ void k_attn(const float* __restrict__ hs,
                       const float* __restrict__ Wv, const float* __restrict__ bv,
                       float* __restrict__ out) {
    int blk = blockIdx.x;
    int t = threadIdx.x;
    __shared__ __align__(16) float w2s[DD];
    __shared__ __align__(16) float hbars[DD];
    __shared__ int   toks[RCNT];
    __shared__ float att[RCNT];
    __shared__ float red[256];
    __shared__ float pm[4];
    __shared__ float qbkS;
    __shared__ int ss[RCNT], sd[RCNT];

    if (blk < BB * NH2) {
        int b = blk / NH2, h = blk % NH2;
        const float* hb = hs + (size_t)b * LL * DD;
        if (t < RCNT) toks[t] = g_unp[b * RCNT + t];
        for (int d = t; d < DD; d += 256) w2s[d] = g_w2[((size_t)b * NH2 + h) * DD + d];
        if (t == 0) qbkS = g_qbk[b * NH2 + h];
        __syncthreads();
        // --- logits: 2 threads per token, half a row each ---
        {
            int tok = t >> 1, half = t & 1;
            const float4* hr4 = (const float4*)(hb + (size_t)toks[tok] * DD) + half * 96;
            const float4* wk4 = (const float4*)w2s + half * 96;
            float4 s4 = {0.f, 0.f, 0.f, 0.f};
            for (int d4 = 0; d4 < 96; d4++) {
                float4 w = wk4[d4], x = hr4[d4];
                s4.x += w.x * x.x; s4.y += w.y * x.y; s4.z += w.z * x.z; s4.w += w.w * x.w;
            }
            red[t] = (s4.x + s4.y) + (s4.z + s4.w);
        }
        __syncthreads();
        float lg = -1e30f;
        if (t < RCNT) lg = (qbkS + red[2 * t] + red[2 * t + 1]) * 0.125f;
        // --- softmax ---
        float m = lg;
#pragma unroll
        for (int off = 32; off >= 1; off >>= 1) m = fmaxf(m, __shfl_xor(m, off, 64));
        if ((t & 63) == 0) pm[t >> 6] = m;
        __syncthreads();
        float mx = fmaxf(pm[0], pm[1]);
        float e = (t < RCNT) ? expf(lg - mx) : 0.f;
        float sume = e;
#pragma unroll
        for (int off = 32; off >= 1; off >>= 1) sume += __shfl_xor(sume, off, 64);
        __syncthreads();
        if ((t & 63) == 0) pm[t >> 6] = sume;
        __syncthreads();
        float inv = 1.f / (pm[0] + pm[1]);
        if (t < RCNT) att[t] = e * inv;
        __syncthreads();
        // --- hbar = sum_tok att * H_tok (ascending tok) ---
        if (t < DD / 4) {
            float4 a = {0.f, 0.f, 0.f, 0.f};
            for (int s2 = 0; s2 < RCNT; s2++) {
                float4 x = ((const float4*)(hb + (size_t)toks[s2] * DD))[t];
                float w = att[s2];
                a.x += w * x.x; a.y += w * x.y; a.z += w * x.z; a.w += w * x.w;
            }
            *(float4*)&hbars[4 * t] = a;
        }
        __syncthreads();
        // --- ctx = hbar @ Wv_h + bv (4 partials of 192) ---
        {
            int u = t & 63, part = t >> 6;
            float a = 0.f;
            for (int d = part * 192; d < part * 192 + 192; d++)
                a += hbars[d] * Wv[(size_t)d * UDIM + h * HD + u];
            red[t] = a;
            __syncthreads();
            if (t < HD)
                g_ctx[b * UDIM + h * HD + t] =
                    bv[h * HD + t] + red[t] + red[t + 64] + red[t + 128] + red[t + 192];
        }
        return;
    }

    // ================= output rows 0..384 (copy / unm / merge) ==============
    int rblk = blk - BB * NH2;
    int row = rblk % 385, b = rblk / 385;
    float4* o4 = (float4*)(out + ((size_t)b * 386 + row) * DD);
    if (row == 0) {
        if (t < 192) {
            const float4* s4 = (const float4*)(hs + (size_t)b * LL * DD);
            o4[t] = s4[t];
        }
    } else if (row <= RCNT) {
        int tok = g_unm[b * RCNT + row - 1];
        if (t < 192) {
            const float4* s4 = (const float4*)(hs + ((size_t)b * LL + tok) * DD);
            o4[t] = s4[t];
        }
    } else {
        int j = row - 1 - RCNT;
        if (t < RCNT) { ss[t] = g_srctok[b * RCNT + t]; sd[t] = g_srcdst[b * RCNT + t]; }
        __syncthreads();
        if (t < 192) {
            float4 acc = ((const float4*)(hs + ((size_t)b * LL + 2 * j + 1) * DD))[t];
            float cnt = 1.f;
            for (int s2 = 0; s2 < RCNT; s2++) {   // ascending rank == np.add.at order
                if (sd[s2] == j) {
                    float4 v = ((const float4*)(hs + ((size_t)b * LL + 2 * ss[s2]) * DD))[t];
                    acc.x += v.x; acc.y += v.y; acc.z += v.z; acc.w += v.w;
                    cnt += 1.f;
                }
            }
            float4 r;
            r.x = acc.x / cnt; r.y = acc.y / cnt; r.z = acc.z / cnt; r.w = acc.w / cnt;
            o4[t] = r;
        }
    }
}

// ---------------- K_newtok: row 385 per batch, 4 blocks/batch ---------------
__global__ void k_newtok(const float* __restrict__ Wo, const float* __restrict__ bo,
                         float* __restrict__ out) {
    int b = blockIdx.x >> 2, q = blockIdx.x & 3;
    int t = threadIdx.x;
    __shared__ float c[UDIM];
    c[t] = g_ctx[b * UDIM + t];
    c[t + 192] = g_ctx[b * UDIM + t + 192];
    __syncthreads();
    int dd = q * 192 + t;
    float acc = bo[dd];
    for (int u = 0; u < UDIM; u++)
        acc += c[u] * Wo[(size_t)u * DD + dd];
    out[((size_t)b * 386 + 385) * DD + dd] = acc;
}

extern "C" void kernel_launch(void* const* d_in, const int* in_sizes, int n_in,
                              void* d_out, int out_size, void* d_ws, size_t ws_size,
                              hipStream_t stream) {
    const float* hs = (const float*)d_in[0];
    const float* sc = (const float*)d_in[1];
    const float* Wq = (const float*)d_in[2];
    const float* bq = (const float*)d_in[3];
    const float* Wk = (const float*)d_in[4];
    const float* bk = (const float*)d_in[5];
    const float* Wv = (const float*)d_in[6];
    const float* bv = (const float*)d_in[7];
    const float* Wo = (const float*)d_in[8];
    const float* bo = (const float*)d_in[9];
    float* out = (float*)d_out;
    (void)d_ws; (void)ws_size;

    k_main<<<512 + BB * NHEAD * 4 + BB * NH2, 256, 0, stream>>>(sc, hs, Wq, bq);
    k_seledge<<<BB + BB * NH2, 512, 0, stream>>>(Wk, bk);
    k_attn<<<BB * NH2 + BB * 385, 256, 0, stream>>>(hs, Wv, bv, out);
    k_newtok<<<BB * 4, 192, 0, stream>>>(Wo, bo, out);
}